// Round 7
// baseline (1270.179 us; speedup 1.0000x reference)
//
#include <hip/hip_runtime.h>
#include <math.h>

#define NTOK 577
#define NB 8
#define NC 1024
#define NH 16
#define HD 64
#define M_ROWS (NB*NTOK)               // 4616
#define SZ ((size_t)NB*NH*NTOK*HD)     // 4726784 elements
#define WSZ ((size_t)3*NC*NC)          // 3145728
#define PSZ ((size_t)NC*NC)            // 1048576
#define VTW 608                        // padded key width for VT (19*32)
#define VTSZ ((size_t)NB*NH*HD*VTW)    // 4980736
#define HSTR ((size_t)NTOK*HD)         // 36928 head stride in A-layout

typedef __attribute__((ext_vector_type(8)))  short bf16x8_t;
typedef __attribute__((ext_vector_type(16))) float f32x16_t;

union U4 { unsigned short s[8]; unsigned int u[4]; bf16x8_t v; };

__device__ inline unsigned short f2bf(float x){
    unsigned int u = __float_as_uint(x);
    u = (u + 0x7FFFu + ((u>>16)&1u)) >> 16;
    return (unsigned short)u;
}
__device__ inline float bf2f(unsigned short h){
    return __uint_as_float(((unsigned int)h)<<16);
}
__device__ inline unsigned int cvt_pk(float a, float b){
    unsigned int r;
    asm volatile("v_cvt_pk_bf16_f32 %0, %1, %2" : "=v"(r) : "v"(a), "v"(b));
    return r;
}

// ---------------------------------------------------------------------------
// split fp32 rows -> bf16 hi/lo [nrows][1024]. mode 0: row-major src.
// mode 1: X [N,B,C] gather (row m=b*577+n -> src row n*8+b).
// ---------------------------------------------------------------------------
__global__ __launch_bounds__(256) void split_rows(const float* __restrict__ src,
        unsigned short* __restrict__ dh, unsigned short* __restrict__ dl, int mode)
{
    int row = blockIdx.x, t = threadIdx.x;
    const float* s;
    if (mode == 0) s = src + (size_t)row*NC + 4*t;
    else {
        int b = row / NTOK, n = row % NTOK;
        s = src + ((size_t)n*NB + b)*NC + 4*t;
    }
    float4 v = *(const float4*)s;
    ushort4 hv, lv;
    hv.x = f2bf(v.x); lv.x = f2bf(v.x - bf2f(hv.x));
    hv.y = f2bf(v.y); lv.y = f2bf(v.y - bf2f(hv.y));
    hv.z = f2bf(v.z); lv.z = f2bf(v.z - bf2f(hv.z));
    hv.w = f2bf(v.w); lv.w = f2bf(v.w - bf2f(hv.w));
    *(ushort4*)(dh + (size_t)row*NC + 4*t) = hv;
    *(ushort4*)(dl + (size_t)row*NC + 4*t) = lv;
}

// ---------------------------------------------------------------------------
// qkv GEMM (bf16x3 MFMA): C = A @ B^T + bias. A [4616][1024] split, B [3072][1024]
// split. Epilogue: split-bf16 q/k/v [B,H,577,64] + VT_v [B,H,64,608] (hi of v).
// ---------------------------------------------------------------------------
__global__ __launch_bounds__(256) void gemm_qkv_mfma(
    const unsigned short* __restrict__ Ah, const unsigned short* __restrict__ Al,
    const unsigned short* __restrict__ Bh, const unsigned short* __restrict__ Bl,
    const float* __restrict__ bias,
    unsigned short* __restrict__ qh, unsigned short* __restrict__ ql,
    unsigned short* __restrict__ kh, unsigned short* __restrict__ kl,
    unsigned short* __restrict__ vh, unsigned short* __restrict__ vl,
    unsigned short* __restrict__ vt)
{
    int l = threadIdx.x & 63, w = threadIdx.x >> 6;
    int lq = l & 31, hi = l >> 5;
    int col0 = blockIdx.x*128 + (w & 1)*64;
    int row0 = blockIdx.y*128 + (w >> 1)*64;

    int ar0 = row0 + lq;      if (ar0 >= M_ROWS) ar0 = M_ROWS-1;
    int ar1 = row0 + 32 + lq; if (ar1 >= M_ROWS) ar1 = M_ROWS-1;
    const unsigned short* pa0h = Ah + (size_t)ar0*NC + 8*hi;
    const unsigned short* pa0l = Al + (size_t)ar0*NC + 8*hi;
    const unsigned short* pa1h = Ah + (size_t)ar1*NC + 8*hi;
    const unsigned short* pa1l = Al + (size_t)ar1*NC + 8*hi;
    const unsigned short* pb0h = Bh + (size_t)(col0 + lq)*NC + 8*hi;
    const unsigned short* pb0l = Bl + (size_t)(col0 + lq)*NC + 8*hi;
    const unsigned short* pb1h = Bh + (size_t)(col0 + 32 + lq)*NC + 8*hi;
    const unsigned short* pb1l = Bl + (size_t)(col0 + 32 + lq)*NC + 8*hi;

    f32x16_t acc[2][2];
    #pragma unroll
    for (int i = 0; i < 16; i++){
        acc[0][0][i]=0.f; acc[0][1][i]=0.f; acc[1][0][i]=0.f; acc[1][1][i]=0.f;
    }
    for (int k0 = 0; k0 < NC; k0 += 16){
        bf16x8_t a0h = *(const bf16x8_t*)(pa0h + k0);
        bf16x8_t a1h = *(const bf16x8_t*)(pa1h + k0);
        bf16x8_t b0h = *(const bf16x8_t*)(pb0h + k0);
        bf16x8_t b1h = *(const bf16x8_t*)(pb1h + k0);
        bf16x8_t a0l = *(const bf16x8_t*)(pa0l + k0);
        bf16x8_t a1l = *(const bf16x8_t*)(pa1l + k0);
        bf16x8_t b0l = *(const bf16x8_t*)(pb0l + k0);
        bf16x8_t b1l = *(const bf16x8_t*)(pb1l + k0);
        acc[0][0] = __builtin_amdgcn_mfma_f32_32x32x16_bf16(a0h, b0h, acc[0][0], 0,0,0);
        acc[0][1] = __builtin_amdgcn_mfma_f32_32x32x16_bf16(a0h, b1h, acc[0][1], 0,0,0);
        acc[1][0] = __builtin_amdgcn_mfma_f32_32x32x16_bf16(a1h, b0h, acc[1][0], 0,0,0);
        acc[1][1] = __builtin_amdgcn_mfma_f32_32x32x16_bf16(a1h, b1h, acc[1][1], 0,0,0);
        acc[0][0] = __builtin_amdgcn_mfma_f32_32x32x16_bf16(a0h, b0l, acc[0][0], 0,0,0);
        acc[0][1] = __builtin_amdgcn_mfma_f32_32x32x16_bf16(a0h, b1l, acc[0][1], 0,0,0);
        acc[1][0] = __builtin_amdgcn_mfma_f32_32x32x16_bf16(a1h, b0l, acc[1][0], 0,0,0);
        acc[1][1] = __builtin_amdgcn_mfma_f32_32x32x16_bf16(a1h, b1l, acc[1][1], 0,0,0);
        acc[0][0] = __builtin_amdgcn_mfma_f32_32x32x16_bf16(a0l, b0h, acc[0][0], 0,0,0);
        acc[0][1] = __builtin_amdgcn_mfma_f32_32x32x16_bf16(a0l, b1h, acc[0][1], 0,0,0);
        acc[1][0] = __builtin_amdgcn_mfma_f32_32x32x16_bf16(a1l, b0h, acc[1][0], 0,0,0);
        acc[1][1] = __builtin_amdgcn_mfma_f32_32x32x16_bf16(a1l, b1h, acc[1][1], 0,0,0);
    }
    #pragma unroll
    for (int fn = 0; fn < 2; fn++){
        int colb = col0 + fn*32 + lq;
        float bb = bias[colb];
        int tt = colb >> 10, h = (colb >> 6) & 15, d = colb & 63;
        unsigned short* dsth = (tt == 0) ? qh : (tt == 1 ? kh : vh);
        unsigned short* dstl = (tt == 0) ? ql : (tt == 1 ? kl : vl);
        #pragma unroll
        for (int fm = 0; fm < 2; fm++){
            #pragma unroll
            for (int r = 0; r < 16; r++){
                int orow = row0 + fm*32 + (r&3) + 8*(r>>2) + 4*hi;
                if (orow < M_ROWS){
                    float val = acc[fm][fn][r] + bb;
                    int b = orow / NTOK, n = orow % NTOK;
                    unsigned short hv = f2bf(val);
                    unsigned short lv = f2bf(val - bf2f(hv));
                    size_t idx = ((size_t)(b*NH + h)*NTOK + n)*HD + d;
                    dsth[idx] = hv; dstl[idx] = lv;
                    if (tt == 2)
                        vt[((size_t)(b*NH + h)*HD + d)*VTW + n] = hv;
                }
            }
        }
    }
}

// ---------------------------------------------------------------------------
// proj GEMM (bf16x3 MFMA): A split bf16 in HEAD layout [B,H,577,64] (k = h*64+d),
// B = proj_w split [1024][1024]. out[(n*8+b)*1024+col] = alpha*acc + bias.
// ---------------------------------------------------------------------------
__global__ __launch_bounds__(256) void gemm_proj_mfma(
    const unsigned short* __restrict__ Ah, const unsigned short* __restrict__ Al,
    const unsigned short* __restrict__ Bh, const unsigned short* __restrict__ Bl,
    const float* __restrict__ bias, float alpha, float* __restrict__ out)
{
    int l = threadIdx.x & 63, w = threadIdx.x >> 6;
    int lq = l & 31, hi = l >> 5;
    int col0 = blockIdx.x*128 + (w & 1)*64;
    int row0 = blockIdx.y*128 + (w >> 1)*64;

    int ar0 = row0 + lq;      if (ar0 >= M_ROWS) ar0 = M_ROWS-1;
    int ar1 = row0 + 32 + lq; if (ar1 >= M_ROWS) ar1 = M_ROWS-1;
    int b0 = ar0 / NTOK, n0 = ar0 % NTOK;
    int b1 = ar1 / NTOK, n1 = ar1 % NTOK;
    const size_t rb0 = (size_t)b0*NH*HSTR + (size_t)n0*HD;
    const size_t rb1 = (size_t)b1*NH*HSTR + (size_t)n1*HD;
    const unsigned short* pb0h = Bh + (size_t)(col0 + lq)*NC + 8*hi;
    const unsigned short* pb0l = Bl + (size_t)(col0 + lq)*NC + 8*hi;
    const unsigned short* pb1h = Bh + (size_t)(col0 + 32 + lq)*NC + 8*hi;
    const unsigned short* pb1l = Bl + (size_t)(col0 + 32 + lq)*NC + 8*hi;

    f32x16_t acc[2][2];
    #pragma unroll
    for (int i = 0; i < 16; i++){
        acc[0][0][i]=0.f; acc[0][1][i]=0.f; acc[1][0][i]=0.f; acc[1][1][i]=0.f;
    }
    for (int k0 = 0; k0 < NC; k0 += 16){
        int kk = k0 + 8*hi;
        size_t aoff = (size_t)(kk >> 6)*HSTR + (kk & 63);
        bf16x8_t a0h = *(const bf16x8_t*)(Ah + rb0 + aoff);
        bf16x8_t a1h = *(const bf16x8_t*)(Ah + rb1 + aoff);
        bf16x8_t b0h = *(const bf16x8_t*)(pb0h + k0);
        bf16x8_t b1h = *(const bf16x8_t*)(pb1h + k0);
        bf16x8_t a0l = *(const bf16x8_t*)(Al + rb0 + aoff);
        bf16x8_t a1l = *(const bf16x8_t*)(Al + rb1 + aoff);
        bf16x8_t b0l = *(const bf16x8_t*)(pb0l + k0);
        bf16x8_t b1l = *(const bf16x8_t*)(pb1l + k0);
        acc[0][0] = __builtin_amdgcn_mfma_f32_32x32x16_bf16(a0h, b0h, acc[0][0], 0,0,0);
        acc[0][1] = __builtin_amdgcn_mfma_f32_32x32x16_bf16(a0h, b1h, acc[0][1], 0,0,0);
        acc[1][0] = __builtin_amdgcn_mfma_f32_32x32x16_bf16(a1h, b0h, acc[1][0], 0,0,0);
        acc[1][1] = __builtin_amdgcn_mfma_f32_32x32x16_bf16(a1h, b1h, acc[1][1], 0,0,0);
        acc[0][0] = __builtin_amdgcn_mfma_f32_32x32x16_bf16(a0h, b0l, acc[0][0], 0,0,0);
        acc[0][1] = __builtin_amdgcn_mfma_f32_32x32x16_bf16(a0h, b1l, acc[0][1], 0,0,0);
        acc[1][0] = __builtin_amdgcn_mfma_f32_32x32x16_bf16(a1h, b0l, acc[1][0], 0,0,0);
        acc[1][1] = __builtin_amdgcn_mfma_f32_32x32x16_bf16(a1h, b1l, acc[1][1], 0,0,0);
        acc[0][0] = __builtin_amdgcn_mfma_f32_32x32x16_bf16(a0l, b0h, acc[0][0], 0,0,0);
        acc[0][1] = __builtin_amdgcn_mfma_f32_32x32x16_bf16(a0l, b1h, acc[0][1], 0,0,0);
        acc[1][0] = __builtin_amdgcn_mfma_f32_32x32x16_bf16(a1l, b0h, acc[1][0], 0,0,0);
        acc[1][1] = __builtin_amdgcn_mfma_f32_32x32x16_bf16(a1l, b1h, acc[1][1], 0,0,0);
    }
    #pragma unroll
    for (int fn = 0; fn < 2; fn++){
        int colb = col0 + fn*32 + lq;
        float bb = bias[colb];
        #pragma unroll
        for (int fm = 0; fm < 2; fm++){
            #pragma unroll
            for (int r = 0; r < 16; r++){
                int orow = row0 + fm*32 + (r&3) + 8*(r>>2) + 4*hi;
                if (orow < M_ROWS){
                    int b = orow / NTOK, n = orow % NTOK;
                    out[((size_t)n*NB + b)*NC + colb] = alpha*acc[fm][fn][r] + bb;
                }
            }
        }
    }
}

// ---------------------------------------------------------------------------
// MFMA flash attention, all-bf16 operands. Q,K split [B,H,577,64];
// V via VT [B,H,64,608] (hi bf16, pads zero). Out split bf16 (optional acc).
// Structure identical to the R5/R6-proven kernel; only operand sourcing changed.
// ---------------------------------------------------------------------------
__global__ __launch_bounds__(256) void flash2(
    const unsigned short* __restrict__ Qh, const unsigned short* __restrict__ Ql,
    const unsigned short* __restrict__ Kh, const unsigned short* __restrict__ Kl,
    const unsigned short* __restrict__ VT,
    unsigned short* __restrict__ Ohi, unsigned short* __restrict__ Olo,
    const float* __restrict__ itemp, float cscale, int acc)
{
    int w    = threadIdx.x >> 6;
    int lane = threadIdx.x & 63;
    int bid  = blockIdx.x;
    int bh   = (bid & 7) * 16 + (bid >> 3) / 5;
    int qt   = ((bid >> 3) % 5) * 4 + w;
    if (qt >= 19) return;
    int hi = lane >> 5, lq = lane & 31;
    float scale = itemp ? itemp[bh >> 4] : cscale;
    const size_t base = (size_t)bh * NTOK * HD;
    const size_t vtb  = (size_t)bh * HD * VTW;

    int qrow = qt*32 + lq;
    int qr = qrow < NTOK ? qrow : NTOK-1;
    const size_t qoff = base + (size_t)qr*HD + 8*hi;
    bf16x8_t qfh[4], qfl[4];
    #pragma unroll
    for (int c = 0; c < 4; c++){
        qfh[c] = *(const bf16x8_t*)(Qh + qoff + 16*c);
        qfl[c] = *(const bf16x8_t*)(Ql + qoff + 16*c);
    }

    f32x16_t od0, od1;
    #pragma unroll
    for (int r = 0; r < 16; r++){ od0[r]=0.f; od1[r]=0.f; }
    float m_ = -1e30f, l_ = 0.f;

    for (int kt = 0; kt < 19; kt++){
        int krow = kt*32 + lq;
        int kr = krow < NTOK ? krow : NTOK-1;
        const size_t koff = base + (size_t)kr*HD + 8*hi;
        bf16x8_t kfh[4], kfl[4];
        #pragma unroll
        for (int c = 0; c < 4; c++){
            kfh[c] = *(const bf16x8_t*)(Kh + koff + 16*c);
            kfl[c] = *(const bf16x8_t*)(Kl + koff + 16*c);
        }
        f32x16_t sf;
        #pragma unroll
        for (int r = 0; r < 16; r++) sf[r] = 0.f;
        #pragma unroll
        for (int c = 0; c < 4; c++){
            sf = __builtin_amdgcn_mfma_f32_32x32x16_bf16(kfh[c], qfh[c], sf, 0,0,0);
            sf = __builtin_amdgcn_mfma_f32_32x32x16_bf16(kfh[c], qfl[c], sf, 0,0,0);
            sf = __builtin_amdgcn_mfma_f32_32x32x16_bf16(kfl[c], qfh[c], sf, 0,0,0);
        }
        float p[16];
        float tm = -1e30f;
        if (kt == 18){
            #pragma unroll
            for (int r = 0; r < 16; r++){
                int key = 576 + (r&3) + 8*(r>>2) + 4*hi;
                p[r] = (key < NTOK) ? sf[r]*scale : -1e30f;
                tm = fmaxf(tm, p[r]);
            }
        } else {
            #pragma unroll
            for (int r = 0; r < 16; r++){ p[r] = sf[r]*scale; tm = fmaxf(tm, p[r]); }
        }
        tm = fmaxf(tm, __shfl_xor(tm, 32));
        float mn = fmaxf(m_, tm);
        float corr = __expf(m_ - mn);
        float ps = 0.f;
        #pragma unroll
        for (int r = 0; r < 16; r++){ p[r] = __expf(p[r] - mn); ps += p[r]; }
        ps += __shfl_xor(ps, 32);
        l_ = l_*corr + ps;
        m_ = mn;
        #pragma unroll
        for (int r = 0; r < 16; r++){
            int crow = (r&3) + 8*(r>>2) + 4*hi;
            float cR = __shfl(corr, crow);
            od0[r] *= cR; od1[r] *= cR;
        }

        U4 pa[2];
        #pragma unroll
        for (int ks = 0; ks < 2; ks++){
            unsigned int X0 = cvt_pk(p[8*ks+0], p[8*ks+1]);
            unsigned int X1 = cvt_pk(p[8*ks+2], p[8*ks+3]);
            unsigned int X2 = cvt_pk(p[8*ks+4], p[8*ks+5]);
            unsigned int X3 = cvt_pk(p[8*ks+6], p[8*ks+7]);
            unsigned int Y0 = (unsigned int)__shfl_xor((int)X2, 32);
            unsigned int Y1 = (unsigned int)__shfl_xor((int)X3, 32);
            unsigned int Y2 = (unsigned int)__shfl_xor((int)X0, 32);
            unsigned int Y3 = (unsigned int)__shfl_xor((int)X1, 32);
            pa[ks].u[0] = hi ? Y0 : X0;
            pa[ks].u[1] = hi ? Y1 : X1;
            pa[ks].u[2] = hi ? X2 : Y2;
            pa[ks].u[3] = hi ? X3 : Y3;
        }
        // V B-frags from VT: element j = V[key0+j][d], contiguous in key
        const size_t v0 = vtb + (size_t)lq*VTW      + kt*32 + 8*hi;
        const size_t v1 = vtb + (size_t)(32+lq)*VTW + kt*32 + 8*hi;
        bf16x8_t vf00 = *(const bf16x8_t*)(VT + v0);
        bf16x8_t vf01 = *(const bf16x8_t*)(VT + v0 + 16);
        bf16x8_t vf10 = *(const bf16x8_t*)(VT + v1);
        bf16x8_t vf11 = *(const bf16x8_t*)(VT + v1 + 16);
        od0 = __builtin_amdgcn_mfma_f32_32x32x16_bf16(pa[0].v, vf00, od0, 0,0,0);
        od0 = __builtin_amdgcn_mfma_f32_32x32x16_bf16(pa[1].v, vf01, od0, 0,0,0);
        od1 = __builtin_amdgcn_mfma_f32_32x32x16_bf16(pa[0].v, vf10, od1, 0,0,0);
        od1 = __builtin_amdgcn_mfma_f32_32x32x16_bf16(pa[1].v, vf11, od1, 0,0,0);
    }

    float linv = 1.f / l_;
    #pragma unroll
    for (int r = 0; r < 16; r++){
        int crow = (r&3) + 8*(r>>2) + 4*hi;
        int qg = qt*32 + crow;
        float li = __shfl(linv, crow);
        if (qg < NTOK){
            size_t o0 = base + (size_t)qg*HD + lq;
            float a0 = od0[r]*li, a1 = od1[r]*li;
            if (acc){
                a0 += bf2f(Ohi[o0])    + bf2f(Olo[o0]);
                a1 += bf2f(Ohi[o0+32]) + bf2f(Olo[o0+32]);
            }
            unsigned short h0 = f2bf(a0), h1 = f2bf(a1);
            Ohi[o0] = h0;    Olo[o0]    = f2bf(a0 - bf2f(h0));
            Ohi[o0+32] = h1; Olo[o0+32] = f2bf(a1 - bf2f(h1));
        }
    }
}

// ---------------------------------------------------------------------------
__global__ __launch_bounds__(256) void row_norm(const float* __restrict__ X,
                                                float* __restrict__ rn)
{
    int id = blockIdx.x;
    int b = id / NTOK, n = id % NTOK;
    const float* src = X + ((size_t)n*NB + b)*NC;
    int tid = threadIdx.x;
    float s = 0.f;
    for (int i = tid; i < NC; i += 256) { float t = src[i]; s += t*t; }
    #pragma unroll
    for (int o = 1; o < 64; o <<= 1) s += __shfl_xor(s, o);
    __shared__ float red[4];
    if ((tid & 63) == 0) red[tid >> 6] = s;
    __syncthreads();
    if (tid == 0) rn[id] = sqrtf(red[0] + red[1] + red[2] + red[3]);
}

__global__ __launch_bounds__(256) void calc_invtemp(const float* __restrict__ rn,
                                                    float* __restrict__ it)
{
    int b = blockIdx.x;
    int tid = threadIdx.x;
    float s = 0.f;
    for (int i = tid; i < NTOK; i += 256) s += rn[b*NTOK + i];
    #pragma unroll
    for (int o = 1; o < 64; o <<= 1) s += __shfl_xor(s, o);
    __shared__ float red[4];
    if ((tid & 63) == 0) red[tid >> 6] = s;
    __syncthreads();
    if (tid == 0) it[b] = (red[0]+red[1]+red[2]+red[3]) / (float)NTOK * 0.125f;
}

// ---------------------------------------------------------------------------
// L2-normalize rows of 64: split bf16 in -> split bf16 out (+optional VT hi).
// In-place safe (each thread reads its element before any write).
// ---------------------------------------------------------------------------
__global__ __launch_bounds__(256) void l2n_s2s(const unsigned short* __restrict__ ih,
        const unsigned short* __restrict__ il,
        unsigned short* __restrict__ oh, unsigned short* __restrict__ ol,
        unsigned short* __restrict__ vt)
{
    size_t row = (size_t)blockIdx.x*4 + (threadIdx.x >> 6);
    int lane = threadIdx.x & 63;
    size_t ii = row*HD + lane;
    float x = bf2f(ih[ii]) + bf2f(il[ii]);
    float s = x*x;
    #pragma unroll
    for (int o = 1; o < 64; o <<= 1) s += __shfl_xor(s, o);
    float xn = x / fmaxf(sqrtf(s), 1e-12f);
    unsigned short hv = f2bf(xn);
    oh[ii] = hv;
    ol[ii] = f2bf(xn - bf2f(hv));
    if (vt){
        size_t bh = row / NTOK, n = row % NTOK;
        vt[(bh*HD + lane)*VTW + n] = hv;
    }
}

// ---------------------------------------------------------------------------
extern "C" void kernel_launch(void* const* d_in, const int* in_sizes, int n_in,
                              void* d_out, int out_size, void* d_ws, size_t ws_size,
                              hipStream_t stream)
{
    const float* x      = (const float*)d_in[0];
    const float* qkv_w  = (const float*)d_in[1];
    const float* qkv_b  = (const float*)d_in[2];
    const float* proj_w = (const float*)d_in[3];
    const float* proj_b = (const float*)d_in[4];
    float* out = (float*)d_out;            // [0,SZ)=x_gem, [SZ,2SZ)=x_ori

    unsigned short* w16 = (unsigned short*)d_ws;
    #define SL(i) (w16 + (size_t)(i)*SZ)          // 8 bf16 slots
    unsigned short* VTx = w16 + 8*SZ;             // aliases WQ (disjoint lifetime)
    unsigned short* WQh = VTx;
    unsigned short* WQl = WQh + WSZ;
    unsigned short* VTv = w16 + 8*SZ + 2*WSZ;
    unsigned short* WPh = VTv + VTSZ;
    unsigned short* WPl = WPh + PSZ;
    float* rn = (float*)(WPl + PSZ);
    float* it = rn + M_ROWS;

    dim3 blk(256);
    dim3 gq(24,37), gp(8,37), gfl(640);

    // inv_temp (independent of everything else)
    row_norm<<<dim3(M_ROWS), blk, 0, stream>>>(x, rn);
    calc_invtemp<<<dim3(NB), blk, 0, stream>>>(rn, it);

    // qkv (A=XA in slots 6,7; B=WQ) -> split q(0,1) k(2,3) v(4,5) + VT_v
    hipMemsetAsync(VTv, 0, VTSZ*sizeof(unsigned short), stream);
    split_rows<<<dim3(M_ROWS), blk, 0, stream>>>(x, SL(6), SL(7), 1);
    split_rows<<<dim3(3*NC),  blk, 0, stream>>>(qkv_w, WQh, WQl, 0);
    gemm_qkv_mfma<<<gq, blk, 0, stream>>>(SL(6), SL(7), WQh, WQl, qkv_b,
        SL(0), SL(1), SL(2), SL(3), SL(4), SL(5), VTv);
    // WQ dead -> VT_x region usable
    hipMemsetAsync(VTx, 0, VTSZ*sizeof(unsigned short), stream);

    // x_ori = proj(softmax(q k^T/8) v): attn -> slots (6,7), proj -> out+SZ
    flash2<<<gfl, blk, 0, stream>>>(SL(0),SL(1),SL(2),SL(3), VTv,
        SL(6),SL(7), nullptr, 0.125f, 0);
    split_rows<<<dim3(NC), blk, 0, stream>>>(proj_w, WPh, WPl, 0);
    gemm_proj_mfma<<<gp, blk, 0, stream>>>(SL(6),SL(7), WPh,WPl, proj_b, 1.f,
        out + SZ);

    // xs1 = l2n(v) -> (6,7)+VTx ; ys1 -> (4,5) ; z1 -> (6,7)
    l2n_s2s<<<dim3(18464), blk, 0, stream>>>(SL(4),SL(5), SL(6),SL(7), VTx);
    flash2<<<gfl, blk, 0, stream>>>(SL(6),SL(7),SL(6),SL(7), VTx,
        SL(4),SL(5), it, 0.f, 0);
    l2n_s2s<<<dim3(18464), blk, 0, stream>>>(SL(4),SL(5), SL(6),SL(7), nullptr);
    // xs2 = l2n(k) in-place +VTx ; ys2 -> (4,5) ; z2 -> (2,3)
    l2n_s2s<<<dim3(18464), blk, 0, stream>>>(SL(2),SL(3), SL(2),SL(3), VTx);
    flash2<<<gfl, blk, 0, stream>>>(SL(2),SL(3),SL(2),SL(3), VTx,
        SL(4),SL(5), it, 0.f, 0);
    l2n_s2s<<<dim3(18464), blk, 0, stream>>>(SL(4),SL(5), SL(2),SL(3), nullptr);
    // xs3 = l2n(q) in-place +VTx ; ys3 -> (4,5) ; z3 -> (0,1)
    l2n_s2s<<<dim3(18464), blk, 0, stream>>>(SL(0),SL(1), SL(0),SL(1), VTx);
    flash2<<<gfl, blk, 0, stream>>>(SL(0),SL(1),SL(0),SL(1), VTx,
        SL(4),SL(5), it, 0.f, 0);
    l2n_s2s<<<dim3(18464), blk, 0, stream>>>(SL(4),SL(5), SL(0),SL(1), nullptr);

    // sum_i softmax(z_i z_i^T * it) @ v -> (4,5) split-accumulated
    flash2<<<gfl, blk, 0, stream>>>(SL(6),SL(7),SL(6),SL(7), VTv,
        SL(4),SL(5), it, 0.f, 0);
    flash2<<<gfl, blk, 0, stream>>>(SL(2),SL(3),SL(2),SL(3), VTv,
        SL(4),SL(5), it, 0.f, 1);
    flash2<<<gfl, blk, 0, stream>>>(SL(0),SL(1),SL(0),SL(1), VTv,
        SL(4),SL(5), it, 0.f, 1);
    // x_gem = proj(sum/3)
    gemm_proj_mfma<<<gp, blk, 0, stream>>>(SL(4),SL(5), WPh,WPl, proj_b,
        1.f/3.f, out);
    #undef SL
}

// Round 8
// 1246.119 us; speedup vs baseline: 1.0193x; 1.0193x over previous
//
#include <hip/hip_runtime.h>
#include <math.h>

#define NTOK 577
#define NB 8
#define NC 1024
#define NH 16
#define HD 64
#define M_ROWS (NB*NTOK)               // 4616
#define SZ ((size_t)NB*NH*NTOK*HD)     // 4726784 elements
#define WSZ ((size_t)3*NC*NC)          // 3145728
#define PSZ ((size_t)NC*NC)            // 1048576
#define VTW 608                        // padded key width for VT (19*32)
#define VTSZ ((size_t)NB*NH*HD*VTW)    // 4980736
#define HSTR ((size_t)NTOK*HD)         // 36928 head stride in A-layout

typedef __attribute__((ext_vector_type(8)))  short bf16x8_t;
typedef __attribute__((ext_vector_type(8)))  unsigned short u16x8_t;
typedef __attribute__((ext_vector_type(16))) float f32x16_t;

union U4 { unsigned short s[8]; unsigned int u[4]; bf16x8_t v; };

__device__ inline unsigned short f2bf(float x){
    unsigned int u = __float_as_uint(x);
    u = (u + 0x7FFFu + ((u>>16)&1u)) >> 16;
    return (unsigned short)u;
}
__device__ inline float bf2f(unsigned short h){
    return __uint_as_float(((unsigned int)h)<<16);
}
__device__ inline unsigned int cvt_pk(float a, float b){
    unsigned int r;
    asm volatile("v_cvt_pk_bf16_f32 %0, %1, %2" : "=v"(r) : "v"(a), "v"(b));
    return r;
}

// ---------------------------------------------------------------------------
// split fp32 rows -> bf16 hi/lo [nrows][1024]. mode 0: row-major src.
// mode 1: X [N,B,C] gather (row m=b*577+n -> src row n*8+b).
// ---------------------------------------------------------------------------
__global__ __launch_bounds__(256) void split_rows(const float* __restrict__ src,
        unsigned short* __restrict__ dh, unsigned short* __restrict__ dl, int mode)
{
    int row = blockIdx.x, t = threadIdx.x;
    const float* s;
    if (mode == 0) s = src + (size_t)row*NC + 4*t;
    else {
        int b = row / NTOK, n = row % NTOK;
        s = src + ((size_t)n*NB + b)*NC + 4*t;
    }
    float4 v = *(const float4*)s;
    ushort4 hv, lv;
    hv.x = f2bf(v.x); lv.x = f2bf(v.x - bf2f(hv.x));
    hv.y = f2bf(v.y); lv.y = f2bf(v.y - bf2f(hv.y));
    hv.z = f2bf(v.z); lv.z = f2bf(v.z - bf2f(hv.z));
    hv.w = f2bf(v.w); lv.w = f2bf(v.w - bf2f(hv.w));
    *(ushort4*)(dh + (size_t)row*NC + 4*t) = hv;
    *(ushort4*)(dl + (size_t)row*NC + 4*t) = lv;
}

// ---------------------------------------------------------------------------
// Coalesced transpose: src hi-bf16 [BH][577][64] -> dst [BH][64][608], pads=0.
// Block: one (bh, 64-token tile). Reads/writes 32B per lane, LDS staged.
// ---------------------------------------------------------------------------
__global__ __launch_bounds__(256) void transp64(const unsigned short* __restrict__ src,
                                                unsigned short* __restrict__ dst)
{
    __shared__ unsigned short t[64][72];           // 144B rows (16B aligned)
    int bh = blockIdx.y;
    int n0 = blockIdx.x * 64;
    int tid = threadIdx.x;
    int r  = tid >> 2;                             // 0..63
    int c0 = (tid & 3) * 16;                       // 0,16,32,48
    int n = n0 + r;
    if (n < NTOK){
        const unsigned short* s = src + ((size_t)bh*NTOK + n)*HD + c0;
        *(u16x8_t*)&t[r][c0]   = *(const u16x8_t*)s;
        *(u16x8_t*)&t[r][c0+8] = *(const u16x8_t*)(s + 8);
    } else {
        u16x8_t z = (u16x8_t)0;
        *(u16x8_t*)&t[r][c0]   = z;
        *(u16x8_t*)&t[r][c0+8] = z;
    }
    __syncthreads();
    if (n0 + c0 < VTW){
        int d = r;
        U4 o0, o1;
        #pragma unroll
        for (int j = 0; j < 8; j++){ o0.s[j] = t[c0+j][d]; o1.s[j] = t[c0+8+j][d]; }
        unsigned short* dp = dst + ((size_t)bh*HD + d)*VTW + n0 + c0;
        *(u16x8_t*)dp       = (u16x8_t)o0.v;
        *(u16x8_t*)(dp + 8) = (u16x8_t)o1.v;
    }
}

#define QLOAD(a0h,a1h,b0h,b1h,a0l,a1l,b0l,b1l, off) \
    a0h = *(const bf16x8_t*)(pa0h + (off)); \
    a1h = *(const bf16x8_t*)(pa1h + (off)); \
    b0h = *(const bf16x8_t*)(pb0h + (off)); \
    b1h = *(const bf16x8_t*)(pb1h + (off)); \
    a0l = *(const bf16x8_t*)(pa0l + (off)); \
    a1l = *(const bf16x8_t*)(pa1l + (off)); \
    b0l = *(const bf16x8_t*)(pb0l + (off)); \
    b1l = *(const bf16x8_t*)(pb1l + (off));

#define MFMA12(a0h,a1h,b0h,b1h,a0l,a1l,b0l,b1l) \
    acc[0][0] = __builtin_amdgcn_mfma_f32_32x32x16_bf16(a0h, b0h, acc[0][0], 0,0,0); \
    acc[0][1] = __builtin_amdgcn_mfma_f32_32x32x16_bf16(a0h, b1h, acc[0][1], 0,0,0); \
    acc[1][0] = __builtin_amdgcn_mfma_f32_32x32x16_bf16(a1h, b0h, acc[1][0], 0,0,0); \
    acc[1][1] = __builtin_amdgcn_mfma_f32_32x32x16_bf16(a1h, b1h, acc[1][1], 0,0,0); \
    acc[0][0] = __builtin_amdgcn_mfma_f32_32x32x16_bf16(a0h, b0l, acc[0][0], 0,0,0); \
    acc[0][1] = __builtin_amdgcn_mfma_f32_32x32x16_bf16(a0h, b1l, acc[0][1], 0,0,0); \
    acc[1][0] = __builtin_amdgcn_mfma_f32_32x32x16_bf16(a1h, b0l, acc[1][0], 0,0,0); \
    acc[1][1] = __builtin_amdgcn_mfma_f32_32x32x16_bf16(a1h, b1l, acc[1][1], 0,0,0); \
    acc[0][0] = __builtin_amdgcn_mfma_f32_32x32x16_bf16(a0l, b0h, acc[0][0], 0,0,0); \
    acc[0][1] = __builtin_amdgcn_mfma_f32_32x32x16_bf16(a0l, b1h, acc[0][1], 0,0,0); \
    acc[1][0] = __builtin_amdgcn_mfma_f32_32x32x16_bf16(a1l, b0h, acc[1][0], 0,0,0); \
    acc[1][1] = __builtin_amdgcn_mfma_f32_32x32x16_bf16(a1l, b1h, acc[1][1], 0,0,0);

// ---------------------------------------------------------------------------
// qkv GEMM (bf16x3 MFMA, register double-buffered): C = A @ B^T + bias.
// Epilogue: split-bf16 q/k/v [B,H,577,64] (contiguous stores only).
// ---------------------------------------------------------------------------
__global__ __launch_bounds__(256) void gemm_qkv_mfma(
    const unsigned short* __restrict__ Ah, const unsigned short* __restrict__ Al,
    const unsigned short* __restrict__ Bh, const unsigned short* __restrict__ Bl,
    const float* __restrict__ bias,
    unsigned short* __restrict__ qh, unsigned short* __restrict__ ql,
    unsigned short* __restrict__ kh, unsigned short* __restrict__ kl,
    unsigned short* __restrict__ vh, unsigned short* __restrict__ vl)
{
    int l = threadIdx.x & 63, w = threadIdx.x >> 6;
    int lq = l & 31, hi = l >> 5;
    int col0 = blockIdx.x*128 + (w & 1)*64;
    int row0 = blockIdx.y*128 + (w >> 1)*64;

    int ar0 = row0 + lq;      if (ar0 >= M_ROWS) ar0 = M_ROWS-1;
    int ar1 = row0 + 32 + lq; if (ar1 >= M_ROWS) ar1 = M_ROWS-1;
    const unsigned short* pa0h = Ah + (size_t)ar0*NC + 8*hi;
    const unsigned short* pa0l = Al + (size_t)ar0*NC + 8*hi;
    const unsigned short* pa1h = Ah + (size_t)ar1*NC + 8*hi;
    const unsigned short* pa1l = Al + (size_t)ar1*NC + 8*hi;
    const unsigned short* pb0h = Bh + (size_t)(col0 + lq)*NC + 8*hi;
    const unsigned short* pb0l = Bl + (size_t)(col0 + lq)*NC + 8*hi;
    const unsigned short* pb1h = Bh + (size_t)(col0 + 32 + lq)*NC + 8*hi;
    const unsigned short* pb1l = Bl + (size_t)(col0 + 32 + lq)*NC + 8*hi;

    f32x16_t acc[2][2];
    #pragma unroll
    for (int i = 0; i < 16; i++){
        acc[0][0][i]=0.f; acc[0][1][i]=0.f; acc[1][0][i]=0.f; acc[1][1][i]=0.f;
    }
    bf16x8_t Xa0h,Xa1h,Xb0h,Xb1h,Xa0l,Xa1l,Xb0l,Xb1l;
    bf16x8_t Ya0h,Ya1h,Yb0h,Yb1h,Ya0l,Ya1l,Yb0l,Yb1l;
    QLOAD(Xa0h,Xa1h,Xb0h,Xb1h,Xa0l,Xa1l,Xb0l,Xb1l, 0)
    for (int k0 = 0; k0 < NC; k0 += 32){
        QLOAD(Ya0h,Ya1h,Yb0h,Yb1h,Ya0l,Ya1l,Yb0l,Yb1l, k0+16)
        MFMA12(Xa0h,Xa1h,Xb0h,Xb1h,Xa0l,Xa1l,Xb0l,Xb1l)
        int kn = (k0+32 < NC) ? (k0+32) : 0;
        QLOAD(Xa0h,Xa1h,Xb0h,Xb1h,Xa0l,Xa1l,Xb0l,Xb1l, kn)
        MFMA12(Ya0h,Ya1h,Yb0h,Yb1h,Ya0l,Ya1l,Yb0l,Yb1l)
    }
    #pragma unroll
    for (int fn = 0; fn < 2; fn++){
        int colb = col0 + fn*32 + lq;
        float bb = bias[colb];
        int tt = colb >> 10, h = (colb >> 6) & 15, d = colb & 63;
        unsigned short* dsth = (tt == 0) ? qh : (tt == 1 ? kh : vh);
        unsigned short* dstl = (tt == 0) ? ql : (tt == 1 ? kl : vl);
        #pragma unroll
        for (int fm = 0; fm < 2; fm++){
            #pragma unroll
            for (int r = 0; r < 16; r++){
                int orow = row0 + fm*32 + (r&3) + 8*(r>>2) + 4*hi;
                if (orow < M_ROWS){
                    float val = acc[fm][fn][r] + bb;
                    int b = orow / NTOK, n = orow % NTOK;
                    unsigned short hv = f2bf(val);
                    unsigned short lv = f2bf(val - bf2f(hv));
                    size_t idx = ((size_t)(b*NH + h)*NTOK + n)*HD + d;
                    dsth[idx] = hv; dstl[idx] = lv;
                }
            }
        }
    }
}

// ---------------------------------------------------------------------------
// proj GEMM (bf16x3 MFMA, register double-buffered). A split bf16 in HEAD
// layout [B,H,577,64] (k = h*64+d); B = proj_w split [1024][1024].
// ---------------------------------------------------------------------------
__global__ __launch_bounds__(256) void gemm_proj_mfma(
    const unsigned short* __restrict__ Ah, const unsigned short* __restrict__ Al,
    const unsigned short* __restrict__ Bh, const unsigned short* __restrict__ Bl,
    const float* __restrict__ bias, float alpha, float* __restrict__ out)
{
    int l = threadIdx.x & 63, w = threadIdx.x >> 6;
    int lq = l & 31, hi = l >> 5;
    int col0 = blockIdx.x*128 + (w & 1)*64;
    int row0 = blockIdx.y*128 + (w >> 1)*64;

    int ar0 = row0 + lq;      if (ar0 >= M_ROWS) ar0 = M_ROWS-1;
    int ar1 = row0 + 32 + lq; if (ar1 >= M_ROWS) ar1 = M_ROWS-1;
    int b0 = ar0 / NTOK, n0 = ar0 % NTOK;
    int b1 = ar1 / NTOK, n1 = ar1 % NTOK;
    const size_t rb0 = (size_t)b0*NH*HSTR + (size_t)n0*HD;
    const size_t rb1 = (size_t)b1*NH*HSTR + (size_t)n1*HD;
    const unsigned short* pb0h = Bh + (size_t)(col0 + lq)*NC + 8*hi;
    const unsigned short* pb0l = Bl + (size_t)(col0 + lq)*NC + 8*hi;
    const unsigned short* pb1h = Bh + (size_t)(col0 + 32 + lq)*NC + 8*hi;
    const unsigned short* pb1l = Bl + (size_t)(col0 + 32 + lq)*NC + 8*hi;

    f32x16_t acc[2][2];
    #pragma unroll
    for (int i = 0; i < 16; i++){
        acc[0][0][i]=0.f; acc[0][1][i]=0.f; acc[1][0][i]=0.f; acc[1][1][i]=0.f;
    }
    bf16x8_t Xa0h,Xa1h,Xb0h,Xb1h,Xa0l,Xa1l,Xb0l,Xb1l;
    bf16x8_t Ya0h,Ya1h,Yb0h,Yb1h,Ya0l,Ya1l,Yb0l,Yb1l;
    #define PLOADA(a0h,a1h,a0l,a1l, kb) { \
        int kk = (kb) + 8*hi; \
        size_t aoff = (size_t)(kk >> 6)*HSTR + (kk & 63); \
        a0h = *(const bf16x8_t*)(Ah + rb0 + aoff); \
        a1h = *(const bf16x8_t*)(Ah + rb1 + aoff); \
        a0l = *(const bf16x8_t*)(Al + rb0 + aoff); \
        a1l = *(const bf16x8_t*)(Al + rb1 + aoff); }
    #define PLOADB(b0h,b1h,b0l,b1l, off) \
        b0h = *(const bf16x8_t*)(pb0h + (off)); \
        b1h = *(const bf16x8_t*)(pb1h + (off)); \
        b0l = *(const bf16x8_t*)(pb0l + (off)); \
        b1l = *(const bf16x8_t*)(pb1l + (off));
    PLOADA(Xa0h,Xa1h,Xa0l,Xa1l, 0)
    PLOADB(Xb0h,Xb1h,Xb0l,Xb1l, 0)
    for (int k0 = 0; k0 < NC; k0 += 32){
        PLOADA(Ya0h,Ya1h,Ya0l,Ya1l, k0+16)
        PLOADB(Yb0h,Yb1h,Yb0l,Yb1l, k0+16)
        MFMA12(Xa0h,Xa1h,Xb0h,Xb1h,Xa0l,Xa1l,Xb0l,Xb1l)
        int kn = (k0+32 < NC) ? (k0+32) : 0;
        PLOADA(Xa0h,Xa1h,Xa0l,Xa1l, kn)
        PLOADB(Xb0h,Xb1h,Xb0l,Xb1l, kn)
        MFMA12(Ya0h,Ya1h,Yb0h,Yb1h,Ya0l,Ya1l,Yb0l,Yb1l)
    }
    #pragma unroll
    for (int fn = 0; fn < 2; fn++){
        int colb = col0 + fn*32 + lq;
        float bb = bias[colb];
        #pragma unroll
        for (int fm = 0; fm < 2; fm++){
            #pragma unroll
            for (int r = 0; r < 16; r++){
                int orow = row0 + fm*32 + (r&3) + 8*(r>>2) + 4*hi;
                if (orow < M_ROWS){
                    int b = orow / NTOK, n = orow % NTOK;
                    out[((size_t)n*NB + b)*NC + colb] = alpha*acc[fm][fn][r] + bb;
                }
            }
        }
    }
}

// ---------------------------------------------------------------------------
// MFMA flash attention (unchanged from R7 — proven). Q,K split [B,H,577,64];
// V via VT [B,H,64,608] (hi bf16, pads zero). Out split bf16 (optional acc).
// ---------------------------------------------------------------------------
__global__ __launch_bounds__(256) void flash2(
    const unsigned short* __restrict__ Qh, const unsigned short* __restrict__ Ql,
    const unsigned short* __restrict__ Kh, const unsigned short* __restrict__ Kl,
    const unsigned short* __restrict__ VT,
    unsigned short* __restrict__ Ohi, unsigned short* __restrict__ Olo,
    const float* __restrict__ itemp, float cscale, int acc)
{
    int w    = threadIdx.x >> 6;
    int lane = threadIdx.x & 63;
    int bid  = blockIdx.x;
    int bh   = (bid & 7) * 16 + (bid >> 3) / 5;
    int qt   = ((bid >> 3) % 5) * 4 + w;
    if (qt >= 19) return;
    int hi = lane >> 5, lq = lane & 31;
    float scale = itemp ? itemp[bh >> 4] : cscale;
    const size_t base = (size_t)bh * NTOK * HD;
    const size_t vtb  = (size_t)bh * HD * VTW;

    int qrow = qt*32 + lq;
    int qr = qrow < NTOK ? qrow : NTOK-1;
    const size_t qoff = base + (size_t)qr*HD + 8*hi;
    bf16x8_t qfh[4], qfl[4];
    #pragma unroll
    for (int c = 0; c < 4; c++){
        qfh[c] = *(const bf16x8_t*)(Qh + qoff + 16*c);
        qfl[c] = *(const bf16x8_t*)(Ql + qoff + 16*c);
    }

    f32x16_t od0, od1;
    #pragma unroll
    for (int r = 0; r < 16; r++){ od0[r]=0.f; od1[r]=0.f; }
    float m_ = -1e30f, l_ = 0.f;

    for (int kt = 0; kt < 19; kt++){
        int krow = kt*32 + lq;
        int kr = krow < NTOK ? krow : NTOK-1;
        const size_t koff = base + (size_t)kr*HD + 8*hi;
        bf16x8_t kfh[4], kfl[4];
        #pragma unroll
        for (int c = 0; c < 4; c++){
            kfh[c] = *(const bf16x8_t*)(Kh + koff + 16*c);
            kfl[c] = *(const bf16x8_t*)(Kl + koff + 16*c);
        }
        f32x16_t sf;
        #pragma unroll
        for (int r = 0; r < 16; r++) sf[r] = 0.f;
        #pragma unroll
        for (int c = 0; c < 4; c++){
            sf = __builtin_amdgcn_mfma_f32_32x32x16_bf16(kfh[c], qfh[c], sf, 0,0,0);
            sf = __builtin_amdgcn_mfma_f32_32x32x16_bf16(kfh[c], qfl[c], sf, 0,0,0);
            sf = __builtin_amdgcn_mfma_f32_32x32x16_bf16(kfl[c], qfh[c], sf, 0,0,0);
        }
        float p[16];
        float tm = -1e30f;
        if (kt == 18){
            #pragma unroll
            for (int r = 0; r < 16; r++){
                int key = 576 + (r&3) + 8*(r>>2) + 4*hi;
                p[r] = (key < NTOK) ? sf[r]*scale : -1e30f;
                tm = fmaxf(tm, p[r]);
            }
        } else {
            #pragma unroll
            for (int r = 0; r < 16; r++){ p[r] = sf[r]*scale; tm = fmaxf(tm, p[r]); }
        }
        tm = fmaxf(tm, __shfl_xor(tm, 32));
        float mn = fmaxf(m_, tm);
        float corr = __expf(m_ - mn);
        float ps = 0.f;
        #pragma unroll
        for (int r = 0; r < 16; r++){ p[r] = __expf(p[r] - mn); ps += p[r]; }
        ps += __shfl_xor(ps, 32);
        l_ = l_*corr + ps;
        m_ = mn;
        #pragma unroll
        for (int r = 0; r < 16; r++){
            int crow = (r&3) + 8*(r>>2) + 4*hi;
            float cR = __shfl(corr, crow);
            od0[r] *= cR; od1[r] *= cR;
        }

        U4 pa[2];
        #pragma unroll
        for (int ks = 0; ks < 2; ks++){
            unsigned int X0 = cvt_pk(p[8*ks+0], p[8*ks+1]);
            unsigned int X1 = cvt_pk(p[8*ks+2], p[8*ks+3]);
            unsigned int X2 = cvt_pk(p[8*ks+4], p[8*ks+5]);
            unsigned int X3 = cvt_pk(p[8*ks+6], p[8*ks+7]);
            unsigned int Y0 = (unsigned int)__shfl_xor((int)X2, 32);
            unsigned int Y1 = (unsigned int)__shfl_xor((int)X3, 32);
            unsigned int Y2 = (unsigned int)__shfl_xor((int)X0, 32);
            unsigned int Y3 = (unsigned int)__shfl_xor((int)X1, 32);
            pa[ks].u[0] = hi ? Y0 : X0;
            pa[ks].u[1] = hi ? Y1 : X1;
            pa[ks].u[2] = hi ? X2 : Y2;
            pa[ks].u[3] = hi ? X3 : Y3;
        }
        const size_t v0 = vtb + (size_t)lq*VTW      + kt*32 + 8*hi;
        const size_t v1 = vtb + (size_t)(32+lq)*VTW + kt*32 + 8*hi;
        bf16x8_t vf00 = *(const bf16x8_t*)(VT + v0);
        bf16x8_t vf01 = *(const bf16x8_t*)(VT + v0 + 16);
        bf16x8_t vf10 = *(const bf16x8_t*)(VT + v1);
        bf16x8_t vf11 = *(const bf16x8_t*)(VT + v1 + 16);
        od0 = __builtin_amdgcn_mfma_f32_32x32x16_bf16(pa[0].v, vf00, od0, 0,0,0);
        od0 = __builtin_amdgcn_mfma_f32_32x32x16_bf16(pa[1].v, vf01, od0, 0,0,0);
        od1 = __builtin_amdgcn_mfma_f32_32x32x16_bf16(pa[0].v, vf10, od1, 0,0,0);
        od1 = __builtin_amdgcn_mfma_f32_32x32x16_bf16(pa[1].v, vf11, od1, 0,0,0);
    }

    float linv = 1.f / l_;
    #pragma unroll
    for (int r = 0; r < 16; r++){
        int crow = (r&3) + 8*(r>>2) + 4*hi;
        int qg = qt*32 + crow;
        float li = __shfl(linv, crow);
        if (qg < NTOK){
            size_t o0 = base + (size_t)qg*HD + lq;
            float a0 = od0[r]*li, a1 = od1[r]*li;
            if (acc){
                a0 += bf2f(Ohi[o0])    + bf2f(Olo[o0]);
                a1 += bf2f(Ohi[o0+32]) + bf2f(Olo[o0+32]);
            }
            unsigned short h0 = f2bf(a0), h1 = f2bf(a1);
            Ohi[o0] = h0;    Olo[o0]    = f2bf(a0 - bf2f(h0));
            Ohi[o0+32] = h1; Olo[o0+32] = f2bf(a1 - bf2f(h1));
        }
    }
}

// ---------------------------------------------------------------------------
__global__ __launch_bounds__(256) void row_norm(const float* __restrict__ X,
                                                float* __restrict__ rn)
{
    int id = blockIdx.x;
    int b = id / NTOK, n = id % NTOK;
    const float* src = X + ((size_t)n*NB + b)*NC;
    int tid = threadIdx.x;
    float s = 0.f;
    for (int i = tid; i < NC; i += 256) { float t = src[i]; s += t*t; }
    #pragma unroll
    for (int o = 1; o < 64; o <<= 1) s += __shfl_xor(s, o);
    __shared__ float red[4];
    if ((tid & 63) == 0) red[tid >> 6] = s;
    __syncthreads();
    if (tid == 0) rn[id] = sqrtf(red[0] + red[1] + red[2] + red[3]);
}

__global__ __launch_bounds__(256) void calc_invtemp(const float* __restrict__ rn,
                                                    float* __restrict__ it)
{
    int b = blockIdx.x;
    int tid = threadIdx.x;
    float s = 0.f;
    for (int i = tid; i < NTOK; i += 256) s += rn[b*NTOK + i];
    #pragma unroll
    for (int o = 1; o < 64; o <<= 1) s += __shfl_xor(s, o);
    __shared__ float red[4];
    if ((tid & 63) == 0) red[tid >> 6] = s;
    __syncthreads();
    if (tid == 0) it[b] = (red[0]+red[1]+red[2]+red[3]) / (float)NTOK * 0.125f;
}

// ---------------------------------------------------------------------------
// L2-normalize rows of 64: split bf16 in -> split bf16 out. In-place safe.
// ---------------------------------------------------------------------------
__global__ __launch_bounds__(256) void l2n_s2s(const unsigned short* __restrict__ ih,
        const unsigned short* __restrict__ il,
        unsigned short* __restrict__ oh, unsigned short* __restrict__ ol)
{
    size_t row = (size_t)blockIdx.x*4 + (threadIdx.x >> 6);
    int lane = threadIdx.x & 63;
    size_t ii = row*HD + lane;
    float x = bf2f(ih[ii]) + bf2f(il[ii]);
    float s = x*x;
    #pragma unroll
    for (int o = 1; o < 64; o <<= 1) s += __shfl_xor(s, o);
    float xn = x / fmaxf(sqrtf(s), 1e-12f);
    unsigned short hv = f2bf(xn);
    oh[ii] = hv;
    ol[ii] = f2bf(xn - bf2f(hv));
}

// ---------------------------------------------------------------------------
extern "C" void kernel_launch(void* const* d_in, const int* in_sizes, int n_in,
                              void* d_out, int out_size, void* d_ws, size_t ws_size,
                              hipStream_t stream)
{
    const float* x      = (const float*)d_in[0];
    const float* qkv_w  = (const float*)d_in[1];
    const float* qkv_b  = (const float*)d_in[2];
    const float* proj_w = (const float*)d_in[3];
    const float* proj_b = (const float*)d_in[4];
    float* out = (float*)d_out;            // [0,SZ)=x_gem, [SZ,2SZ)=x_ori

    unsigned short* w16 = (unsigned short*)d_ws;
    #define SL(i) (w16 + (size_t)(i)*SZ)          // 8 bf16 slots
    unsigned short* VTx = w16 + 8*SZ;             // aliases WQ (disjoint lifetime)
    unsigned short* WQh = VTx;
    unsigned short* WQl = WQh + WSZ;
    unsigned short* VTv = w16 + 8*SZ + 2*WSZ;
    unsigned short* WPh = VTv + VTSZ;
    unsigned short* WPl = WPh + PSZ;
    float* rn = (float*)(WPl + PSZ);
    float* it = rn + M_ROWS;

    dim3 blk(256);
    dim3 gq(24,37), gp(8,37), gfl(640), gt(10,128);

    // inv_temp
    row_norm<<<dim3(M_ROWS), blk, 0, stream>>>(x, rn);
    calc_invtemp<<<dim3(NB), blk, 0, stream>>>(rn, it);

    // qkv: split inputs, MFMA gemm -> q(0,1) k(2,3) v(4,5); then VTv
    split_rows<<<dim3(M_ROWS), blk, 0, stream>>>(x, SL(6), SL(7), 1);
    split_rows<<<dim3(3*NC),  blk, 0, stream>>>(qkv_w, WQh, WQl, 0);
    gemm_qkv_mfma<<<gq, blk, 0, stream>>>(SL(6), SL(7), WQh, WQl, qkv_b,
        SL(0), SL(1), SL(2), SL(3), SL(4), SL(5));
    transp64<<<gt, blk, 0, stream>>>(SL(4), VTv);

    // x_ori = proj(softmax(q k^T/8) v): attn -> slots (6,7), proj -> out+SZ
    flash2<<<gfl, blk, 0, stream>>>(SL(0),SL(1),SL(2),SL(3), VTv,
        SL(6),SL(7), nullptr, 0.125f, 0);
    split_rows<<<dim3(NC), blk, 0, stream>>>(proj_w, WPh, WPl, 0);
    gemm_proj_mfma<<<gp, blk, 0, stream>>>(SL(6),SL(7), WPh,WPl, proj_b, 1.f,
        out + SZ);

    // xs1 = l2n(v) -> (6,7); VTx; ys1 -> (4,5) ; z1 -> (6,7)
    l2n_s2s<<<dim3(18464), blk, 0, stream>>>(SL(4),SL(5), SL(6),SL(7));
    transp64<<<gt, blk, 0, stream>>>(SL(6), VTx);
    flash2<<<gfl, blk, 0, stream>>>(SL(6),SL(7),SL(6),SL(7), VTx,
        SL(4),SL(5), it, 0.f, 0);
    l2n_s2s<<<dim3(18464), blk, 0, stream>>>(SL(4),SL(5), SL(6),SL(7));
    // xs2 = l2n(k) in-place; VTx; ys2 -> (4,5) ; z2 -> (2,3)
    l2n_s2s<<<dim3(18464), blk, 0, stream>>>(SL(2),SL(3), SL(2),SL(3));
    transp64<<<gt, blk, 0, stream>>>(SL(2), VTx);
    flash2<<<gfl, blk, 0, stream>>>(SL(2),SL(3),SL(2),SL(3), VTx,
        SL(4),SL(5), it, 0.f, 0);
    l2n_s2s<<<dim3(18464), blk, 0, stream>>>(SL(4),SL(5), SL(2),SL(3));
    // xs3 = l2n(q) in-place; VTx; ys3 -> (4,5) ; z3 -> (0,1)
    l2n_s2s<<<dim3(18464), blk, 0, stream>>>(SL(0),SL(1), SL(0),SL(1));
    transp64<<<gt, blk, 0, stream>>>(SL(0), VTx);
    flash2<<<gfl, blk, 0, stream>>>(SL(0),SL(1),SL(0),SL(1), VTx,
        SL(4),SL(5), it, 0.f, 0);
    l2n_s2s<<<dim3(18464), blk, 0, stream>>>(SL(4),SL(5), SL(0),SL(1));

    // sum_i softmax(z_i z_i^T * it) @ v -> (4,5) split-accumulated
    flash2<<<gfl, blk, 0, stream>>>(SL(6),SL(7),SL(6),SL(7), VTv,
        SL(4),SL(5), it, 0.f, 0);
    flash2<<<gfl, blk, 0, stream>>>(SL(2),SL(3),SL(2),SL(3), VTv,
        SL(4),SL(5), it, 0.f, 1);
    flash2<<<gfl, blk, 0, stream>>>(SL(0),SL(1),SL(0),SL(1), VTv,
        SL(4),SL(5), it, 0.f, 1);
    // x_gem = proj(sum/3)
    gemm_proj_mfma<<<gp, blk, 0, stream>>>(SL(4),SL(5), WPh,WPl, proj_b,
        1.f/3.f, out);
    #undef SL
}

// Round 9
// 933.675 us; speedup vs baseline: 1.3604x; 1.3346x over previous
//
#include <hip/hip_runtime.h>
#include <math.h>

#define NTOK 577
#define NB 8
#define NC 1024
#define NH 16
#define HD 64
#define M_ROWS (NB*NTOK)               // 4616
#define SZ ((size_t)NB*NH*NTOK*HD)     // 4726784 elements
#define WSZ ((size_t)3*NC*NC)          // 3145728
#define PSZ ((size_t)NC*NC)            // 1048576
#define VTW 608                        // padded key width for VT (19*32)
#define VTSZ ((size_t)NB*NH*HD*VTW)    // 4980736
#define HSTR ((size_t)NTOK*HD)         // 36928 head stride in A-layout
#define LP 36                          // padded LDS row (32 data + 4 pad)

typedef __attribute__((ext_vector_type(8)))  short bf16x8_t;
typedef __attribute__((ext_vector_type(8)))  unsigned short u16x8_t;
typedef __attribute__((ext_vector_type(16))) float f32x16_t;

union U4 { unsigned short s[8]; unsigned int u[4]; bf16x8_t v; };

__device__ inline unsigned short f2bf(float x){
    unsigned int u = __float_as_uint(x);
    u = (u + 0x7FFFu + ((u>>16)&1u)) >> 16;
    return (unsigned short)u;
}
__device__ inline float bf2f(unsigned short h){
    return __uint_as_float(((unsigned int)h)<<16);
}
__device__ inline unsigned int cvt_pk(float a, float b){
    unsigned int r;
    asm volatile("v_cvt_pk_bf16_f32 %0, %1, %2" : "=v"(r) : "v"(a), "v"(b));
    return r;
}

// ---------------------------------------------------------------------------
// split fp32 rows -> bf16 hi/lo [nrows][1024]. mode 0: row-major src.
// mode 1: X [N,B,C] gather (row m=b*577+n -> src row n*8+b).
// ---------------------------------------------------------------------------
__global__ __launch_bounds__(256) void split_rows(const float* __restrict__ src,
        unsigned short* __restrict__ dh, unsigned short* __restrict__ dl, int mode)
{
    int row = blockIdx.x, t = threadIdx.x;
    const float* s;
    if (mode == 0) s = src + (size_t)row*NC + 4*t;
    else {
        int b = row / NTOK, n = row % NTOK;
        s = src + ((size_t)n*NB + b)*NC + 4*t;
    }
    float4 v = *(const float4*)s;
    ushort4 hv, lv;
    hv.x = f2bf(v.x); lv.x = f2bf(v.x - bf2f(hv.x));
    hv.y = f2bf(v.y); lv.y = f2bf(v.y - bf2f(hv.y));
    hv.z = f2bf(v.z); lv.z = f2bf(v.z - bf2f(hv.z));
    hv.w = f2bf(v.w); lv.w = f2bf(v.w - bf2f(hv.w));
    *(ushort4*)(dh + (size_t)row*NC + 4*t) = hv;
    *(ushort4*)(dl + (size_t)row*NC + 4*t) = lv;
}

// ---------------------------------------------------------------------------
// Coalesced transpose: src hi-bf16 [BH][577][64] -> dst [BH][64][608], pads=0.
// ---------------------------------------------------------------------------
__global__ __launch_bounds__(256) void transp64(const unsigned short* __restrict__ src,
                                                unsigned short* __restrict__ dst)
{
    __shared__ unsigned short t[64][72];
    int bh = blockIdx.y;
    int n0 = blockIdx.x * 64;
    int tid = threadIdx.x;
    int r  = tid >> 2;
    int c0 = (tid & 3) * 16;
    int n = n0 + r;
    if (n < NTOK){
        const unsigned short* s = src + ((size_t)bh*NTOK + n)*HD + c0;
        *(u16x8_t*)&t[r][c0]   = *(const u16x8_t*)s;
        *(u16x8_t*)&t[r][c0+8] = *(const u16x8_t*)(s + 8);
    } else {
        u16x8_t z = (u16x8_t)0;
        *(u16x8_t*)&t[r][c0]   = z;
        *(u16x8_t*)&t[r][c0+8] = z;
    }
    __syncthreads();
    if (n0 + c0 < VTW){
        int d = r;
        U4 o0, o1;
        #pragma unroll
        for (int j = 0; j < 8; j++){ o0.s[j] = t[c0+j][d]; o1.s[j] = t[c0+8+j][d]; }
        unsigned short* dp = dst + ((size_t)bh*HD + d)*VTW + n0 + c0;
        *(u16x8_t*)dp       = (u16x8_t)o0.v;
        *(u16x8_t*)(dp + 8) = (u16x8_t)o1.v;
    }
}

#define MFMA12(a0h,a1h,b0h,b1h,a0l,a1l,b0l,b1l) \
    acc[0][0] = __builtin_amdgcn_mfma_f32_32x32x16_bf16(a0h, b0h, acc[0][0], 0,0,0); \
    acc[0][1] = __builtin_amdgcn_mfma_f32_32x32x16_bf16(a0h, b1h, acc[0][1], 0,0,0); \
    acc[1][0] = __builtin_amdgcn_mfma_f32_32x32x16_bf16(a1h, b0h, acc[1][0], 0,0,0); \
    acc[1][1] = __builtin_amdgcn_mfma_f32_32x32x16_bf16(a1h, b1h, acc[1][1], 0,0,0); \
    acc[0][0] = __builtin_amdgcn_mfma_f32_32x32x16_bf16(a0h, b0l, acc[0][0], 0,0,0); \
    acc[0][1] = __builtin_amdgcn_mfma_f32_32x32x16_bf16(a0h, b1l, acc[0][1], 0,0,0); \
    acc[1][0] = __builtin_amdgcn_mfma_f32_32x32x16_bf16(a1h, b0l, acc[1][0], 0,0,0); \
    acc[1][1] = __builtin_amdgcn_mfma_f32_32x32x16_bf16(a1h, b1l, acc[1][1], 0,0,0); \
    acc[0][0] = __builtin_amdgcn_mfma_f32_32x32x16_bf16(a0l, b0h, acc[0][0], 0,0,0); \
    acc[0][1] = __builtin_amdgcn_mfma_f32_32x32x16_bf16(a0l, b1h, acc[0][1], 0,0,0); \
    acc[1][0] = __builtin_amdgcn_mfma_f32_32x32x16_bf16(a1l, b0h, acc[1][0], 0,0,0); \
    acc[1][1] = __builtin_amdgcn_mfma_f32_32x32x16_bf16(a1l, b1h, acc[1][1], 0,0,0);

// ---------------------------------------------------------------------------
// qkv GEMM, LDS-staged (128x128 tile, BK=32, padded LDS rows, 4 waves 2x2).
// C = A @ B^T + bias -> split-bf16 q/k/v [B,H,577,64].
// ---------------------------------------------------------------------------
__global__ __launch_bounds__(256) void gemm_qkv_mfma(
    const unsigned short* __restrict__ Ah, const unsigned short* __restrict__ Al,
    const unsigned short* __restrict__ Bh, const unsigned short* __restrict__ Bl,
    const float* __restrict__ bias,
    unsigned short* __restrict__ qh, unsigned short* __restrict__ ql,
    unsigned short* __restrict__ kh, unsigned short* __restrict__ kl,
    unsigned short* __restrict__ vh, unsigned short* __restrict__ vl)
{
    __shared__ unsigned short ahs[128][LP], als[128][LP];
    __shared__ unsigned short bhs[128][LP], bls[128][LP];
    int t = threadIdx.x;
    int l = t & 63, w = t >> 6;
    int lq = l & 31, hi = l >> 5;
    int wr = w >> 1, wc = w & 1;
    int col0 = blockIdx.x*128, row0 = blockIdx.y*128;

    int srow[2], scol[2], sa[2];
    #pragma unroll
    for (int i = 0; i < 2; i++){
        int idx = i*256 + t;
        srow[i] = idx >> 2;
        scol[i] = (idx & 3) * 8;
        int ar = row0 + srow[i]; if (ar >= M_ROWS) ar = M_ROWS-1;
        sa[i] = ar;
    }

    f32x16_t acc[2][2];
    #pragma unroll
    for (int i = 0; i < 16; i++){
        acc[0][0][i]=0.f; acc[0][1][i]=0.f; acc[1][0][i]=0.f; acc[1][1][i]=0.f;
    }

    for (int k0 = 0; k0 < NC; k0 += 32){
        if (k0) __syncthreads();
        #pragma unroll
        for (int i = 0; i < 2; i++){
            size_t ao = (size_t)sa[i]*NC + k0 + scol[i];
            size_t bo = (size_t)(col0 + srow[i])*NC + k0 + scol[i];
            u16x8_t va  = *(const u16x8_t*)(Ah + ao);
            u16x8_t va2 = *(const u16x8_t*)(Al + ao);
            u16x8_t vb  = *(const u16x8_t*)(Bh + bo);
            u16x8_t vb2 = *(const u16x8_t*)(Bl + bo);
            *(u16x8_t*)&ahs[srow[i]][scol[i]] = va;
            *(u16x8_t*)&als[srow[i]][scol[i]] = va2;
            *(u16x8_t*)&bhs[srow[i]][scol[i]] = vb;
            *(u16x8_t*)&bls[srow[i]][scol[i]] = vb2;
        }
        __syncthreads();
        #pragma unroll
        for (int kk = 0; kk < 2; kk++){
            int co = kk*16 + 8*hi;
            bf16x8_t a0h = *(const bf16x8_t*)&ahs[wr*64+lq][co];
            bf16x8_t a1h = *(const bf16x8_t*)&ahs[wr*64+32+lq][co];
            bf16x8_t b0h = *(const bf16x8_t*)&bhs[wc*64+lq][co];
            bf16x8_t b1h = *(const bf16x8_t*)&bhs[wc*64+32+lq][co];
            bf16x8_t a0l = *(const bf16x8_t*)&als[wr*64+lq][co];
            bf16x8_t a1l = *(const bf16x8_t*)&als[wr*64+32+lq][co];
            bf16x8_t b0l = *(const bf16x8_t*)&bls[wc*64+lq][co];
            bf16x8_t b1l = *(const bf16x8_t*)&bls[wc*64+32+lq][co];
            MFMA12(a0h,a1h,b0h,b1h,a0l,a1l,b0l,b1l)
        }
    }

    int colW = col0 + wc*64, rowW = row0 + wr*64;
    #pragma unroll
    for (int fn = 0; fn < 2; fn++){
        int colb = colW + fn*32 + lq;
        float bb = bias[colb];
        int tt = colb >> 10, h = (colb >> 6) & 15, d = colb & 63;
        unsigned short* dsth = (tt == 0) ? qh : (tt == 1 ? kh : vh);
        unsigned short* dstl = (tt == 0) ? ql : (tt == 1 ? kl : vl);
        #pragma unroll
        for (int fm = 0; fm < 2; fm++){
            #pragma unroll
            for (int r = 0; r < 16; r++){
                int orow = rowW + fm*32 + (r&3) + 8*(r>>2) + 4*hi;
                if (orow < M_ROWS){
                    float val = acc[fm][fn][r] + bb;
                    int b = orow / NTOK, n = orow % NTOK;
                    unsigned short hv = f2bf(val);
                    unsigned short lv = f2bf(val - bf2f(hv));
                    size_t idx = ((size_t)(b*NH + h)*NTOK + n)*HD + d;
                    dsth[idx] = hv; dstl[idx] = lv;
                }
            }
        }
    }
}

// ---------------------------------------------------------------------------
// proj GEMM, LDS-staged (64x128 tile, BK=32). A split bf16 in HEAD layout
// [B,H,577,64] (k = h*64+d); B = proj_w split [1024][1024].
// Waves 2x2: (wr rows 32) x (wc cols 64, 2 frags).
// ---------------------------------------------------------------------------
__global__ __launch_bounds__(256) void gemm_proj_mfma(
    const unsigned short* __restrict__ Ah, const unsigned short* __restrict__ Al,
    const unsigned short* __restrict__ Bh, const unsigned short* __restrict__ Bl,
    const float* __restrict__ bias, float alpha, float* __restrict__ out)
{
    __shared__ unsigned short ahs[64][LP], als[64][LP];
    __shared__ unsigned short bhs[128][LP], bls[128][LP];
    int t = threadIdx.x;
    int l = t & 63, w = t >> 6;
    int lq = l & 31, hi = l >> 5;
    int wr = w >> 1, wc = w & 1;
    int col0 = blockIdx.x*128, row0 = blockIdx.y*64;

    // A staging: 1 load/thread. row = t>>2 (0..63), col8 = (t&3)*8
    int sarow = t >> 2, sacol = (t & 3) * 8;
    int ar = row0 + sarow; if (ar >= M_ROWS) ar = M_ROWS-1;
    size_t abase = (size_t)(ar / NTOK)*NH*HSTR + (size_t)(ar % NTOK)*HD;
    // B staging: 2 loads/thread
    int sbrow[2], sbcol[2];
    #pragma unroll
    for (int i = 0; i < 2; i++){
        int idx = i*256 + t;
        sbrow[i] = idx >> 2;
        sbcol[i] = (idx & 3) * 8;
    }

    f32x16_t acc[2];
    #pragma unroll
    for (int i = 0; i < 16; i++){ acc[0][i]=0.f; acc[1][i]=0.f; }

    for (int k0 = 0; k0 < NC; k0 += 32){
        if (k0) __syncthreads();
        {
            int kk = k0 + sacol;
            size_t ao = abase + (size_t)(kk >> 6)*HSTR + (kk & 63);
            u16x8_t va  = *(const u16x8_t*)(Ah + ao);
            u16x8_t va2 = *(const u16x8_t*)(Al + ao);
            *(u16x8_t*)&ahs[sarow][sacol] = va;
            *(u16x8_t*)&als[sarow][sacol] = va2;
            #pragma unroll
            for (int i = 0; i < 2; i++){
                size_t bo = (size_t)(col0 + sbrow[i])*NC + k0 + sbcol[i];
                u16x8_t vb  = *(const u16x8_t*)(Bh + bo);
                u16x8_t vb2 = *(const u16x8_t*)(Bl + bo);
                *(u16x8_t*)&bhs[sbrow[i]][sbcol[i]] = vb;
                *(u16x8_t*)&bls[sbrow[i]][sbcol[i]] = vb2;
            }
        }
        __syncthreads();
        #pragma unroll
        for (int kk = 0; kk < 2; kk++){
            int co = kk*16 + 8*hi;
            bf16x8_t a0h = *(const bf16x8_t*)&ahs[wr*32+lq][co];
            bf16x8_t a0l = *(const bf16x8_t*)&als[wr*32+lq][co];
            bf16x8_t b0h = *(const bf16x8_t*)&bhs[wc*64+lq][co];
            bf16x8_t b1h = *(const bf16x8_t*)&bhs[wc*64+32+lq][co];
            bf16x8_t b0l = *(const bf16x8_t*)&bls[wc*64+lq][co];
            bf16x8_t b1l = *(const bf16x8_t*)&bls[wc*64+32+lq][co];
            acc[0] = __builtin_amdgcn_mfma_f32_32x32x16_bf16(a0h, b0h, acc[0], 0,0,0);
            acc[1] = __builtin_amdgcn_mfma_f32_32x32x16_bf16(a0h, b1h, acc[1], 0,0,0);
            acc[0] = __builtin_amdgcn_mfma_f32_32x32x16_bf16(a0h, b0l, acc[0], 0,0,0);
            acc[1] = __builtin_amdgcn_mfma_f32_32x32x16_bf16(a0h, b1l, acc[1], 0,0,0);
            acc[0] = __builtin_amdgcn_mfma_f32_32x32x16_bf16(a0l, b0h, acc[0], 0,0,0);
            acc[1] = __builtin_amdgcn_mfma_f32_32x32x16_bf16(a0l, b1h, acc[1], 0,0,0);
        }
    }

    #pragma unroll
    for (int fn = 0; fn < 2; fn++){
        int colb = col0 + wc*64 + fn*32 + lq;
        float bb = bias[colb];
        #pragma unroll
        for (int r = 0; r < 16; r++){
            int orow = row0 + wr*32 + (r&3) + 8*(r>>2) + 4*hi;
            if (orow < M_ROWS){
                int b = orow / NTOK, n = orow % NTOK;
                out[((size_t)n*NB + b)*NC + colb] = alpha*acc[fn][r] + bb;
            }
        }
    }
}

// ---------------------------------------------------------------------------
// MFMA flash attention (inner math proven R5-R8). Q,K split [B,H,577,64];
// V via VT [B,H,64,608]. Out split bf16 (optional split-accumulate).
// ---------------------------------------------------------------------------
__global__ __launch_bounds__(256) void flash2(
    const unsigned short* __restrict__ Qh, const unsigned short* __restrict__ Ql,
    const unsigned short* __restrict__ Kh, const unsigned short* __restrict__ Kl,
    const unsigned short* __restrict__ VT,
    unsigned short* __restrict__ Ohi, unsigned short* __restrict__ Olo,
    const float* __restrict__ itemp, float cscale, int acc)
{
    int w    = threadIdx.x >> 6;
    int lane = threadIdx.x & 63;
    int bid  = blockIdx.x;
    int bh   = (bid & 7) * 16 + (bid >> 3) / 5;
    int qt   = ((bid >> 3) % 5) * 4 + w;
    if (qt >= 19) return;
    int hi = lane >> 5, lq = lane & 31;
    float scale = itemp ? itemp[bh >> 4] : cscale;
    const size_t base = (size_t)bh * NTOK * HD;
    const size_t vtb  = (size_t)bh * HD * VTW;

    int qrow = qt*32 + lq;
    int qr = qrow < NTOK ? qrow : NTOK-1;
    const size_t qoff = base + (size_t)qr*HD + 8*hi;
    bf16x8_t qfh[4], qfl[4];
    #pragma unroll
    for (int c = 0; c < 4; c++){
        qfh[c] = *(const bf16x8_t*)(Qh + qoff + 16*c);
        qfl[c] = *(const bf16x8_t*)(Ql + qoff + 16*c);
    }

    f32x16_t od0, od1;
    #pragma unroll
    for (int r = 0; r < 16; r++){ od0[r]=0.f; od1[r]=0.f; }
    float m_ = -1e30f, l_ = 0.f;

    for (int kt = 0; kt < 19; kt++){
        int krow = kt*32 + lq;
        int kr = krow < NTOK ? krow : NTOK-1;
        const size_t koff = base + (size_t)kr*HD + 8*hi;
        bf16x8_t kfh[4], kfl[4];
        #pragma unroll
        for (int c = 0; c < 4; c++){
            kfh[c] = *(const bf16x8_t*)(Kh + koff + 16*c);
            kfl[c] = *(const bf16x8_t*)(Kl + koff + 16*c);
        }
        f32x16_t sf;
        #pragma unroll
        for (int r = 0; r < 16; r++) sf[r] = 0.f;
        #pragma unroll
        for (int c = 0; c < 4; c++){
            sf = __builtin_amdgcn_mfma_f32_32x32x16_bf16(kfh[c], qfh[c], sf, 0,0,0);
            sf = __builtin_amdgcn_mfma_f32_32x32x16_bf16(kfh[c], qfl[c], sf, 0,0,0);
            sf = __builtin_amdgcn_mfma_f32_32x32x16_bf16(kfl[c], qfh[c], sf, 0,0,0);
        }
        float p[16];
        float tm = -1e30f;
        if (kt == 18){
            #pragma unroll
            for (int r = 0; r < 16; r++){
                int key = 576 + (r&3) + 8*(r>>2) + 4*hi;
                p[r] = (key < NTOK) ? sf[r]*scale : -1e30f;
                tm = fmaxf(tm, p[r]);
            }
        } else {
            #pragma unroll
            for (int r = 0; r < 16; r++){ p[r] = sf[r]*scale; tm = fmaxf(tm, p[r]); }
        }
        tm = fmaxf(tm, __shfl_xor(tm, 32));
        float mn = fmaxf(m_, tm);
        float corr = __expf(m_ - mn);
        float ps = 0.f;
        #pragma unroll
        for (int r = 0; r < 16; r++){ p[r] = __expf(p[r] - mn); ps += p[r]; }
        ps += __shfl_xor(ps, 32);
        l_ = l_*corr + ps;
        m_ = mn;
        #pragma unroll
        for (int r = 0; r < 16; r++){
            int crow = (r&3) + 8*(r>>2) + 4*hi;
            float cR = __shfl(corr, crow);
            od0[r] *= cR; od1[r] *= cR;
        }

        U4 pa[2];
        #pragma unroll
        for (int ks = 0; ks < 2; ks++){
            unsigned int X0 = cvt_pk(p[8*ks+0], p[8*ks+1]);
            unsigned int X1 = cvt_pk(p[8*ks+2], p[8*ks+3]);
            unsigned int X2 = cvt_pk(p[8*ks+4], p[8*ks+5]);
            unsigned int X3 = cvt_pk(p[8*ks+6], p[8*ks+7]);
            unsigned int Y0 = (unsigned int)__shfl_xor((int)X2, 32);
            unsigned int Y1 = (unsigned int)__shfl_xor((int)X3, 32);
            unsigned int Y2 = (unsigned int)__shfl_xor((int)X0, 32);
            unsigned int Y3 = (unsigned int)__shfl_xor((int)X1, 32);
            pa[ks].u[0] = hi ? Y0 : X0;
            pa[ks].u[1] = hi ? Y1 : X1;
            pa[ks].u[2] = hi ? X2 : Y2;
            pa[ks].u[3] = hi ? X3 : Y3;
        }
        const size_t v0 = vtb + (size_t)lq*VTW      + kt*32 + 8*hi;
        const size_t v1 = vtb + (size_t)(32+lq)*VTW + kt*32 + 8*hi;
        bf16x8_t vf00 = *(const bf16x8_t*)(VT + v0);
        bf16x8_t vf01 = *(const bf16x8_t*)(VT + v0 + 16);
        bf16x8_t vf10 = *(const bf16x8_t*)(VT + v1);
        bf16x8_t vf11 = *(const bf16x8_t*)(VT + v1 + 16);
        od0 = __builtin_amdgcn_mfma_f32_32x32x16_bf16(pa[0].v, vf00, od0, 0,0,0);
        od0 = __builtin_amdgcn_mfma_f32_32x32x16_bf16(pa[1].v, vf01, od0, 0,0,0);
        od1 = __builtin_amdgcn_mfma_f32_32x32x16_bf16(pa[0].v, vf10, od1, 0,0,0);
        od1 = __builtin_amdgcn_mfma_f32_32x32x16_bf16(pa[1].v, vf11, od1, 0,0,0);
    }

    float linv = 1.f / l_;
    #pragma unroll
    for (int r = 0; r < 16; r++){
        int crow = (r&3) + 8*(r>>2) + 4*hi;
        int qg = qt*32 + crow;
        float li = __shfl(linv, crow);
        if (qg < NTOK){
            size_t o0 = base + (size_t)qg*HD + lq;
            float a0 = od0[r]*li, a1 = od1[r]*li;
            if (acc){
                a0 += bf2f(Ohi[o0])    + bf2f(Olo[o0]);
                a1 += bf2f(Ohi[o0+32]) + bf2f(Olo[o0+32]);
            }
            unsigned short h0 = f2bf(a0), h1 = f2bf(a1);
            Ohi[o0] = h0;    Olo[o0]    = f2bf(a0 - bf2f(h0));
            Ohi[o0+32] = h1; Olo[o0+32] = f2bf(a1 - bf2f(h1));
        }
    }
}

// ---------------------------------------------------------------------------
// Fused final stage: osum = sum_i softmax(z_i z_i^T * it) @ v for 3 z's,
// sharing VT across i, one output write (split bf16). Same inner math.
// ---------------------------------------------------------------------------
__global__ __launch_bounds__(256) void flash3(
    const unsigned short* __restrict__ Z0h, const unsigned short* __restrict__ Z0l,
    const unsigned short* __restrict__ Z1h, const unsigned short* __restrict__ Z1l,
    const unsigned short* __restrict__ Z2h, const unsigned short* __restrict__ Z2l,
    const unsigned short* __restrict__ VT,
    unsigned short* __restrict__ Ohi, unsigned short* __restrict__ Olo,
    const float* __restrict__ itemp)
{
    int w    = threadIdx.x >> 6;
    int lane = threadIdx.x & 63;
    int bid  = blockIdx.x;
    int bh   = (bid & 7) * 16 + (bid >> 3) / 5;
    int qt   = ((bid >> 3) % 5) * 4 + w;
    if (qt >= 19) return;
    int hi = lane >> 5, lq = lane & 31;
    float scale = itemp[bh >> 4];
    const size_t base = (size_t)bh * NTOK * HD;
    const size_t vtb  = (size_t)bh * HD * VTW;

    int qrow = qt*32 + lq;
    int qr = qrow < NTOK ? qrow : NTOK-1;
    const size_t qoff = base + (size_t)qr*HD + 8*hi;

    f32x16_t os0, os1;
    #pragma unroll
    for (int r = 0; r < 16; r++){ os0[r]=0.f; os1[r]=0.f; }

    for (int i = 0; i < 3; i++){
        const unsigned short *Qh, *Ql;
        if (i == 0){ Qh = Z0h; Ql = Z0l; }
        else if (i == 1){ Qh = Z1h; Ql = Z1l; }
        else { Qh = Z2h; Ql = Z2l; }

        bf16x8_t qfh[4], qfl[4];
        #pragma unroll
        for (int c = 0; c < 4; c++){
            qfh[c] = *(const bf16x8_t*)(Qh + qoff + 16*c);
            qfl[c] = *(const bf16x8_t*)(Ql + qoff + 16*c);
        }
        f32x16_t od0, od1;
        #pragma unroll
        for (int r = 0; r < 16; r++){ od0[r]=0.f; od1[r]=0.f; }
        float m_ = -1e30f, l_ = 0.f;

        for (int kt = 0; kt < 19; kt++){
            int krow = kt*32 + lq;
            int kr = krow < NTOK ? krow : NTOK-1;
            const size_t koff = base + (size_t)kr*HD + 8*hi;
            bf16x8_t kfh[4], kfl[4];
            #pragma unroll
            for (int c = 0; c < 4; c++){
                kfh[c] = *(const bf16x8_t*)(Qh + koff + 16*c);
                kfl[c] = *(const bf16x8_t*)(Ql + koff + 16*c);
            }
            f32x16_t sf;
            #pragma unroll
            for (int r = 0; r < 16; r++) sf[r] = 0.f;
            #pragma unroll
            for (int c = 0; c < 4; c++){
                sf = __builtin_amdgcn_mfma_f32_32x32x16_bf16(kfh[c], qfh[c], sf, 0,0,0);
                sf = __builtin_amdgcn_mfma_f32_32x32x16_bf16(kfh[c], qfl[c], sf, 0,0,0);
                sf = __builtin_amdgcn_mfma_f32_32x32x16_bf16(kfl[c], qfh[c], sf, 0,0,0);
            }
            float p[16];
            float tm = -1e30f;
            if (kt == 18){
                #pragma unroll
                for (int r = 0; r < 16; r++){
                    int key = 576 + (r&3) + 8*(r>>2) + 4*hi;
                    p[r] = (key < NTOK) ? sf[r]*scale : -1e30f;
                    tm = fmaxf(tm, p[r]);
                }
            } else {
                #pragma unroll
                for (int r = 0; r < 16; r++){ p[r] = sf[r]*scale; tm = fmaxf(tm, p[r]); }
            }
            tm = fmaxf(tm, __shfl_xor(tm, 32));
            float mn = fmaxf(m_, tm);
            float corr = __expf(m_ - mn);
            float ps = 0.f;
            #pragma unroll
            for (int r = 0; r < 16; r++){ p[r] = __expf(p[r] - mn); ps += p[r]; }
            ps += __shfl_xor(ps, 32);
            l_ = l_*corr + ps;
            m_ = mn;
            #pragma unroll
            for (int r = 0; r < 16; r++){
                int crow = (r&3) + 8*(r>>2) + 4*hi;
                float cR = __shfl(corr, crow);
                od0[r] *= cR; od1[r] *= cR;
            }

            U4 pa[2];
            #pragma unroll
            for (int ks = 0; ks < 2; ks++){
                unsigned int X0 = cvt_pk(p[8*ks+0], p[8*ks+1]);
                unsigned int X1 = cvt_pk(p[8*ks+2], p[8*ks+3]);
                unsigned int X2 = cvt_pk(p[8*ks+4], p[8*ks+5]);
                unsigned int X3 = cvt_pk(p[8*ks+6], p[8*ks+7]);
                unsigned int Y0 = (unsigned int)__shfl_xor((int)X2, 32);
                unsigned int Y1 = (unsigned int)__shfl_xor((int)X3, 32);
                unsigned int Y2 = (unsigned int)__shfl_xor((int)X0, 32);
                unsigned int Y3 = (unsigned int)__shfl_xor((int)X1, 32);
                pa[ks].u[0] = hi ? Y0 : X0;
                pa[ks].u[1] = hi ? Y1 : X1;
                pa[ks].u[2] = hi ? X2 : Y2;
                pa[ks].u[3] = hi ? X3 : Y3;
            }
            const size_t v0 = vtb + (size_t)lq*VTW      + kt*32 + 8*hi;
            const size_t v1 = vtb + (size_t)(32+lq)*VTW + kt*32 + 8*hi;
            bf16x8_t vf00 = *(const bf16x8_t*)(VT + v0);
            bf16x8_t vf01 = *(const bf16x8_t*)(VT + v0 + 16);
            bf16x8_t vf10 = *(const bf16x8_t*)(VT + v1);
            bf16x8_t vf11 = *(const bf16x8_t*)(VT + v1 + 16);
            od0 = __builtin_amdgcn_mfma_f32_32x32x16_bf16(pa[0].v, vf00, od0, 0,0,0);
            od0 = __builtin_amdgcn_mfma_f32_32x32x16_bf16(pa[1].v, vf01, od0, 0,0,0);
            od1 = __builtin_amdgcn_mfma_f32_32x32x16_bf16(pa[0].v, vf10, od1, 0,0,0);
            od1 = __builtin_amdgcn_mfma_f32_32x32x16_bf16(pa[1].v, vf11, od1, 0,0,0);
        }
        float linv = 1.f / l_;
        #pragma unroll
        for (int r = 0; r < 16; r++){
            int crow = (r&3) + 8*(r>>2) + 4*hi;
            float li = __shfl(linv, crow);
            os0[r] += od0[r]*li;
            os1[r] += od1[r]*li;
        }
    }

    #pragma unroll
    for (int r = 0; r < 16; r++){
        int crow = (r&3) + 8*(r>>2) + 4*hi;
        int qg = qt*32 + crow;
        if (qg < NTOK){
            size_t o0 = base + (size_t)qg*HD + lq;
            float a0 = os0[r], a1 = os1[r];
            unsigned short h0 = f2bf(a0), h1 = f2bf(a1);
            Ohi[o0] = h0;    Olo[o0]    = f2bf(a0 - bf2f(h0));
            Ohi[o0+32] = h1; Olo[o0+32] = f2bf(a1 - bf2f(h1));
        }
    }
}

// ---------------------------------------------------------------------------
__global__ __launch_bounds__(256) void row_norm(const float* __restrict__ X,
                                                float* __restrict__ rn)
{
    int id = blockIdx.x;
    int b = id / NTOK, n = id % NTOK;
    const float* src = X + ((size_t)n*NB + b)*NC;
    int tid = threadIdx.x;
    float s = 0.f;
    for (int i = tid; i < NC; i += 256) { float t = src[i]; s += t*t; }
    #pragma unroll
    for (int o = 1; o < 64; o <<= 1) s += __shfl_xor(s, o);
    __shared__ float red[4];
    if ((tid & 63) == 0) red[tid >> 6] = s;
    __syncthreads();
    if (tid == 0) rn[id] = sqrtf(red[0] + red[1] + red[2] + red[3]);
}

__global__ __launch_bounds__(256) void calc_invtemp(const float* __restrict__ rn,
                                                    float* __restrict__ it)
{
    int b = blockIdx.x;
    int tid = threadIdx.x;
    float s = 0.f;
    for (int i = tid; i < NTOK; i += 256) s += rn[b*NTOK + i];
    #pragma unroll
    for (int o = 1; o < 64; o <<= 1) s += __shfl_xor(s, o);
    __shared__ float red[4];
    if ((tid & 63) == 0) red[tid >> 6] = s;
    __syncthreads();
    if (tid == 0) it[b] = (red[0]+red[1]+red[2]+red[3]) / (float)NTOK * 0.125f;
}

// ---------------------------------------------------------------------------
__global__ __launch_bounds__(256) void l2n_s2s(const unsigned short* __restrict__ ih,
        const unsigned short* __restrict__ il,
        unsigned short* __restrict__ oh, unsigned short* __restrict__ ol)
{
    size_t row = (size_t)blockIdx.x*4 + (threadIdx.x >> 6);
    int lane = threadIdx.x & 63;
    size_t ii = row*HD + lane;
    float x = bf2f(ih[ii]) + bf2f(il[ii]);
    float s = x*x;
    #pragma unroll
    for (int o = 1; o < 64; o <<= 1) s += __shfl_xor(s, o);
    float xn = x / fmaxf(sqrtf(s), 1e-12f);
    unsigned short hv = f2bf(xn);
    oh[ii] = hv;
    ol[ii] = f2bf(xn - bf2f(hv));
}

// ---------------------------------------------------------------------------
extern "C" void kernel_launch(void* const* d_in, const int* in_sizes, int n_in,
                              void* d_out, int out_size, void* d_ws, size_t ws_size,
                              hipStream_t stream)
{
    const float* x      = (const float*)d_in[0];
    const float* qkv_w  = (const float*)d_in[1];
    const float* qkv_b  = (const float*)d_in[2];
    const float* proj_w = (const float*)d_in[3];
    const float* proj_b = (const float*)d_in[4];
    float* out = (float*)d_out;            // [0,SZ)=x_gem, [SZ,2SZ)=x_ori

    unsigned short* w16 = (unsigned short*)d_ws;
    #define SL(i) (w16 + (size_t)(i)*SZ)          // 8 bf16 slots
    unsigned short* VTx = w16 + 8*SZ;             // aliases WQ (disjoint lifetime)
    unsigned short* WQh = VTx;
    unsigned short* WQl = WQh + WSZ;
    unsigned short* VTv = w16 + 8*SZ + 2*WSZ;
    unsigned short* WPh = VTv + VTSZ;
    unsigned short* WPl = WPh + PSZ;
    float* rn = (float*)(WPl + PSZ);
    float* it = rn + M_ROWS;

    dim3 blk(256);
    dim3 gq(24,37), gp(8,73), gfl(640), gt(10,128);

    // inv_temp
    row_norm<<<dim3(M_ROWS), blk, 0, stream>>>(x, rn);
    calc_invtemp<<<dim3(NB), blk, 0, stream>>>(rn, it);

    // qkv: split inputs, LDS-staged MFMA gemm -> q(0,1) k(2,3) v(4,5); then VTv
    split_rows<<<dim3(M_ROWS), blk, 0, stream>>>(x, SL(6), SL(7), 1);
    split_rows<<<dim3(3*NC),  blk, 0, stream>>>(qkv_w, WQh, WQl, 0);
    gemm_qkv_mfma<<<gq, blk, 0, stream>>>(SL(6), SL(7), WQh, WQl, qkv_b,
        SL(0), SL(1), SL(2), SL(3), SL(4), SL(5));
    transp64<<<gt, blk, 0, stream>>>(SL(4), VTv);

    // x_ori = proj(softmax(q k^T/8) v): attn -> slots (6,7), proj -> out+SZ
    flash2<<<gfl, blk, 0, stream>>>(SL(0),SL(1),SL(2),SL(3), VTv,
        SL(6),SL(7), nullptr, 0.125f, 0);
    split_rows<<<dim3(NC), blk, 0, stream>>>(proj_w, WPh, WPl, 0);
    gemm_proj_mfma<<<gp, blk, 0, stream>>>(SL(6),SL(7), WPh,WPl, proj_b, 1.f,
        out + SZ);

    // xs1 = l2n(v) -> (6,7); VTx; ys1 -> (4,5) ; z1 -> (6,7)
    l2n_s2s<<<dim3(18464), blk, 0, stream>>>(SL(4),SL(5), SL(6),SL(7));
    transp64<<<gt, blk, 0, stream>>>(SL(6), VTx);
    flash2<<<gfl, blk, 0, stream>>>(SL(6),SL(7),SL(6),SL(7), VTx,
        SL(4),SL(5), it, 0.f, 0);
    l2n_s2s<<<dim3(18464), blk, 0, stream>>>(SL(4),SL(5), SL(6),SL(7));
    // xs2 = l2n(k) in-place; VTx; ys2 -> (4,5) ; z2 -> (2,3)
    l2n_s2s<<<dim3(18464), blk, 0, stream>>>(SL(2),SL(3), SL(2),SL(3));
    transp64<<<gt, blk, 0, stream>>>(SL(2), VTx);
    flash2<<<gfl, blk, 0, stream>>>(SL(2),SL(3),SL(2),SL(3), VTx,
        SL(4),SL(5), it, 0.f, 0);
    l2n_s2s<<<dim3(18464), blk, 0, stream>>>(SL(4),SL(5), SL(2),SL(3));
    // xs3 = l2n(q) in-place; VTx; ys3 -> (4,5) ; z3 -> (0,1)
    l2n_s2s<<<dim3(18464), blk, 0, stream>>>(SL(0),SL(1), SL(0),SL(1));
    transp64<<<gt, blk, 0, stream>>>(SL(0), VTx);
    flash2<<<gfl, blk, 0, stream>>>(SL(0),SL(1),SL(0),SL(1), VTx,
        SL(4),SL(5), it, 0.f, 0);
    l2n_s2s<<<dim3(18464), blk, 0, stream>>>(SL(4),SL(5), SL(0),SL(1));

    // fused: sum_i softmax(z_i z_i^T * it) @ v -> (4,5)
    flash3<<<gfl, blk, 0, stream>>>(SL(6),SL(7), SL(2),SL(3), SL(0),SL(1),
        VTv, SL(4),SL(5), it);
    // x_gem = proj(sum/3)
    gemm_proj_mfma<<<gp, blk, 0, stream>>>(SL(4),SL(5), WPh,WPl, proj_b,
        1.f/3.f, out);
    #undef SL
}

// Round 10
// 793.666 us; speedup vs baseline: 1.6004x; 1.1764x over previous
//
#include <hip/hip_runtime.h>
#include <math.h>

#define NTOK 577
#define NB 8
#define NC 1024
#define NH 16
#define HD 64
#define M_ROWS (NB*NTOK)               // 4616
#define SZ ((size_t)NB*NH*NTOK*HD)     // 4726784 elements
#define WSZ ((size_t)3*NC*NC)          // 3145728
#define PSZ ((size_t)NC*NC)            // 1048576
#define VTW 608                        // padded key width for VT (19*32)
#define VTSZ ((size_t)NB*NH*HD*VTW)    // 4980736
#define HSTR ((size_t)NTOK*HD)         // 36928 head stride in A-layout
#define LP 36                          // padded LDS row (32 data + 4 pad)

typedef __attribute__((ext_vector_type(8)))  short bf16x8_t;
typedef __attribute__((ext_vector_type(8)))  unsigned short u16x8_t;
typedef __attribute__((ext_vector_type(16))) float f32x16_t;

union U4 { unsigned short s[8]; unsigned int u[4]; bf16x8_t v; };

__device__ inline unsigned short f2bf(float x){
    unsigned int u = __float_as_uint(x);
    u = (u + 0x7FFFu + ((u>>16)&1u)) >> 16;
    return (unsigned short)u;
}
__device__ inline float bf2f(unsigned short h){
    return __uint_as_float(((unsigned int)h)<<16);
}
__device__ inline unsigned int cvt_pk(float a, float b){
    unsigned int r;
    asm volatile("v_cvt_pk_bf16_f32 %0, %1, %2" : "=v"(r) : "v"(a), "v"(b));
    return r;
}

// ---------------------------------------------------------------------------
// split fp32 rows -> bf16 hi/lo [nrows][1024]. mode 0: row-major src.
// mode 1: X [N,B,C] gather (row m=b*577+n -> src row n*8+b).
// ---------------------------------------------------------------------------
__global__ __launch_bounds__(256) void split_rows(const float* __restrict__ src,
        unsigned short* __restrict__ dh, unsigned short* __restrict__ dl, int mode)
{
    int row = blockIdx.x, t = threadIdx.x;
    const float* s;
    if (mode == 0) s = src + (size_t)row*NC + 4*t;
    else {
        int b = row / NTOK, n = row % NTOK;
        s = src + ((size_t)n*NB + b)*NC + 4*t;
    }
    float4 v = *(const float4*)s;
    ushort4 hv, lv;
    hv.x = f2bf(v.x); lv.x = f2bf(v.x - bf2f(hv.x));
    hv.y = f2bf(v.y); lv.y = f2bf(v.y - bf2f(hv.y));
    hv.z = f2bf(v.z); lv.z = f2bf(v.z - bf2f(hv.z));
    hv.w = f2bf(v.w); lv.w = f2bf(v.w - bf2f(hv.w));
    *(ushort4*)(dh + (size_t)row*NC + 4*t) = hv;
    *(ushort4*)(dl + (size_t)row*NC + 4*t) = lv;
}

// ---------------------------------------------------------------------------
// Coalesced transpose: src hi-bf16 [BH][577][64] -> dst [BH][64][608], pads=0.
// ---------------------------------------------------------------------------
__global__ __launch_bounds__(256) void transp64(const unsigned short* __restrict__ src,
                                                unsigned short* __restrict__ dst)
{
    __shared__ unsigned short t[64][72];
    int bh = blockIdx.y;
    int n0 = blockIdx.x * 64;
    int tid = threadIdx.x;
    int r  = tid >> 2;
    int c0 = (tid & 3) * 16;
    int n = n0 + r;
    if (n < NTOK){
        const unsigned short* s = src + ((size_t)bh*NTOK + n)*HD + c0;
        *(u16x8_t*)&t[r][c0]   = *(const u16x8_t*)s;
        *(u16x8_t*)&t[r][c0+8] = *(const u16x8_t*)(s + 8);
    } else {
        u16x8_t z = (u16x8_t)0;
        *(u16x8_t*)&t[r][c0]   = z;
        *(u16x8_t*)&t[r][c0+8] = z;
    }
    __syncthreads();
    if (n0 + c0 < VTW){
        int d = r;
        U4 o0, o1;
        #pragma unroll
        for (int j = 0; j < 8; j++){ o0.s[j] = t[c0+j][d]; o1.s[j] = t[c0+8+j][d]; }
        unsigned short* dp = dst + ((size_t)bh*HD + d)*VTW + n0 + c0;
        *(u16x8_t*)dp       = (u16x8_t)o0.v;
        *(u16x8_t*)(dp + 8) = (u16x8_t)o1.v;
    }
}

#define MFMA12(a0h,a1h,b0h,b1h,a0l,a1l,b0l,b1l) \
    acc[0][0] = __builtin_amdgcn_mfma_f32_32x32x16_bf16(a0h, b0h, acc[0][0], 0,0,0); \
    acc[0][1] = __builtin_amdgcn_mfma_f32_32x32x16_bf16(a0h, b1h, acc[0][1], 0,0,0); \
    acc[1][0] = __builtin_amdgcn_mfma_f32_32x32x16_bf16(a1h, b0h, acc[1][0], 0,0,0); \
    acc[1][1] = __builtin_amdgcn_mfma_f32_32x32x16_bf16(a1h, b1h, acc[1][1], 0,0,0); \
    acc[0][0] = __builtin_amdgcn_mfma_f32_32x32x16_bf16(a0h, b0l, acc[0][0], 0,0,0); \
    acc[0][1] = __builtin_amdgcn_mfma_f32_32x32x16_bf16(a0h, b1l, acc[0][1], 0,0,0); \
    acc[1][0] = __builtin_amdgcn_mfma_f32_32x32x16_bf16(a1h, b0l, acc[1][0], 0,0,0); \
    acc[1][1] = __builtin_amdgcn_mfma_f32_32x32x16_bf16(a1h, b1l, acc[1][1], 0,0,0); \
    acc[0][0] = __builtin_amdgcn_mfma_f32_32x32x16_bf16(a0l, b0h, acc[0][0], 0,0,0); \
    acc[0][1] = __builtin_amdgcn_mfma_f32_32x32x16_bf16(a0l, b1h, acc[0][1], 0,0,0); \
    acc[1][0] = __builtin_amdgcn_mfma_f32_32x32x16_bf16(a1l, b0h, acc[1][0], 0,0,0); \
    acc[1][1] = __builtin_amdgcn_mfma_f32_32x32x16_bf16(a1l, b1h, acc[1][1], 0,0,0);

// ---------------------------------------------------------------------------
// qkv GEMM, LDS-staged (128x128 tile, BK=32, padded LDS rows, 4 waves 2x2).
// ---------------------------------------------------------------------------
__global__ __launch_bounds__(256) void gemm_qkv_mfma(
    const unsigned short* __restrict__ Ah, const unsigned short* __restrict__ Al,
    const unsigned short* __restrict__ Bh, const unsigned short* __restrict__ Bl,
    const float* __restrict__ bias,
    unsigned short* __restrict__ qh, unsigned short* __restrict__ ql,
    unsigned short* __restrict__ kh, unsigned short* __restrict__ kl,
    unsigned short* __restrict__ vh, unsigned short* __restrict__ vl)
{
    __shared__ unsigned short ahs[128][LP], als[128][LP];
    __shared__ unsigned short bhs[128][LP], bls[128][LP];
    int t = threadIdx.x;
    int l = t & 63, w = t >> 6;
    int lq = l & 31, hi = l >> 5;
    int wr = w >> 1, wc = w & 1;
    int col0 = blockIdx.x*128, row0 = blockIdx.y*128;

    int srow[2], scol[2], sa[2];
    #pragma unroll
    for (int i = 0; i < 2; i++){
        int idx = i*256 + t;
        srow[i] = idx >> 2;
        scol[i] = (idx & 3) * 8;
        int ar = row0 + srow[i]; if (ar >= M_ROWS) ar = M_ROWS-1;
        sa[i] = ar;
    }

    f32x16_t acc[2][2];
    #pragma unroll
    for (int i = 0; i < 16; i++){
        acc[0][0][i]=0.f; acc[0][1][i]=0.f; acc[1][0][i]=0.f; acc[1][1][i]=0.f;
    }

    for (int k0 = 0; k0 < NC; k0 += 32){
        if (k0) __syncthreads();
        #pragma unroll
        for (int i = 0; i < 2; i++){
            size_t ao = (size_t)sa[i]*NC + k0 + scol[i];
            size_t bo = (size_t)(col0 + srow[i])*NC + k0 + scol[i];
            u16x8_t va  = *(const u16x8_t*)(Ah + ao);
            u16x8_t va2 = *(const u16x8_t*)(Al + ao);
            u16x8_t vb  = *(const u16x8_t*)(Bh + bo);
            u16x8_t vb2 = *(const u16x8_t*)(Bl + bo);
            *(u16x8_t*)&ahs[srow[i]][scol[i]] = va;
            *(u16x8_t*)&als[srow[i]][scol[i]] = va2;
            *(u16x8_t*)&bhs[srow[i]][scol[i]] = vb;
            *(u16x8_t*)&bls[srow[i]][scol[i]] = vb2;
        }
        __syncthreads();
        #pragma unroll
        for (int kk = 0; kk < 2; kk++){
            int co = kk*16 + 8*hi;
            bf16x8_t a0h = *(const bf16x8_t*)&ahs[wr*64+lq][co];
            bf16x8_t a1h = *(const bf16x8_t*)&ahs[wr*64+32+lq][co];
            bf16x8_t b0h = *(const bf16x8_t*)&bhs[wc*64+lq][co];
            bf16x8_t b1h = *(const bf16x8_t*)&bhs[wc*64+32+lq][co];
            bf16x8_t a0l = *(const bf16x8_t*)&als[wr*64+lq][co];
            bf16x8_t a1l = *(const bf16x8_t*)&als[wr*64+32+lq][co];
            bf16x8_t b0l = *(const bf16x8_t*)&bls[wc*64+lq][co];
            bf16x8_t b1l = *(const bf16x8_t*)&bls[wc*64+32+lq][co];
            MFMA12(a0h,a1h,b0h,b1h,a0l,a1l,b0l,b1l)
        }
    }

    int colW = col0 + wc*64, rowW = row0 + wr*64;
    #pragma unroll
    for (int fn = 0; fn < 2; fn++){
        int colb = colW + fn*32 + lq;
        float bb = bias[colb];
        int tt = colb >> 10, h = (colb >> 6) & 15, d = colb & 63;
        unsigned short* dsth = (tt == 0) ? qh : (tt == 1 ? kh : vh);
        unsigned short* dstl = (tt == 0) ? ql : (tt == 1 ? kl : vl);
        #pragma unroll
        for (int fm = 0; fm < 2; fm++){
            #pragma unroll
            for (int r = 0; r < 16; r++){
                int orow = rowW + fm*32 + (r&3) + 8*(r>>2) + 4*hi;
                if (orow < M_ROWS){
                    float val = acc[fm][fn][r] + bb;
                    int b = orow / NTOK, n = orow % NTOK;
                    unsigned short hv = f2bf(val);
                    unsigned short lv = f2bf(val - bf2f(hv));
                    size_t idx = ((size_t)(b*NH + h)*NTOK + n)*HD + d;
                    dsth[idx] = hv; dstl[idx] = lv;
                }
            }
        }
    }
}

// ---------------------------------------------------------------------------
// proj GEMM, LDS-staged (64x128 tile, BK=32). A split bf16 in HEAD layout.
// ---------------------------------------------------------------------------
__global__ __launch_bounds__(256) void gemm_proj_mfma(
    const unsigned short* __restrict__ Ah, const unsigned short* __restrict__ Al,
    const unsigned short* __restrict__ Bh, const unsigned short* __restrict__ Bl,
    const float* __restrict__ bias, float alpha, float* __restrict__ out)
{
    __shared__ unsigned short ahs[64][LP], als[64][LP];
    __shared__ unsigned short bhs[128][LP], bls[128][LP];
    int t = threadIdx.x;
    int l = t & 63, w = t >> 6;
    int lq = l & 31, hi = l >> 5;
    int wr = w >> 1, wc = w & 1;
    int col0 = blockIdx.x*128, row0 = blockIdx.y*64;

    int sarow = t >> 2, sacol = (t & 3) * 8;
    int ar = row0 + sarow; if (ar >= M_ROWS) ar = M_ROWS-1;
    size_t abase = (size_t)(ar / NTOK)*NH*HSTR + (size_t)(ar % NTOK)*HD;
    int sbrow[2], sbcol[2];
    #pragma unroll
    for (int i = 0; i < 2; i++){
        int idx = i*256 + t;
        sbrow[i] = idx >> 2;
        sbcol[i] = (idx & 3) * 8;
    }

    f32x16_t acc[2];
    #pragma unroll
    for (int i = 0; i < 16; i++){ acc[0][i]=0.f; acc[1][i]=0.f; }

    for (int k0 = 0; k0 < NC; k0 += 32){
        if (k0) __syncthreads();
        {
            int kk = k0 + sacol;
            size_t ao = abase + (size_t)(kk >> 6)*HSTR + (kk & 63);
            u16x8_t va  = *(const u16x8_t*)(Ah + ao);
            u16x8_t va2 = *(const u16x8_t*)(Al + ao);
            *(u16x8_t*)&ahs[sarow][sacol] = va;
            *(u16x8_t*)&als[sarow][sacol] = va2;
            #pragma unroll
            for (int i = 0; i < 2; i++){
                size_t bo = (size_t)(col0 + sbrow[i])*NC + k0 + sbcol[i];
                u16x8_t vb  = *(const u16x8_t*)(Bh + bo);
                u16x8_t vb2 = *(const u16x8_t*)(Bl + bo);
                *(u16x8_t*)&bhs[sbrow[i]][sbcol[i]] = vb;
                *(u16x8_t*)&bls[sbrow[i]][sbcol[i]] = vb2;
            }
        }
        __syncthreads();
        #pragma unroll
        for (int kk = 0; kk < 2; kk++){
            int co = kk*16 + 8*hi;
            bf16x8_t a0h = *(const bf16x8_t*)&ahs[wr*32+lq][co];
            bf16x8_t a0l = *(const bf16x8_t*)&als[wr*32+lq][co];
            bf16x8_t b0h = *(const bf16x8_t*)&bhs[wc*64+lq][co];
            bf16x8_t b1h = *(const bf16x8_t*)&bhs[wc*64+32+lq][co];
            bf16x8_t b0l = *(const bf16x8_t*)&bls[wc*64+lq][co];
            bf16x8_t b1l = *(const bf16x8_t*)&bls[wc*64+32+lq][co];
            acc[0] = __builtin_amdgcn_mfma_f32_32x32x16_bf16(a0h, b0h, acc[0], 0,0,0);
            acc[1] = __builtin_amdgcn_mfma_f32_32x32x16_bf16(a0h, b1h, acc[1], 0,0,0);
            acc[0] = __builtin_amdgcn_mfma_f32_32x32x16_bf16(a0h, b0l, acc[0], 0,0,0);
            acc[1] = __builtin_amdgcn_mfma_f32_32x32x16_bf16(a0h, b1l, acc[1], 0,0,0);
            acc[0] = __builtin_amdgcn_mfma_f32_32x32x16_bf16(a0l, b0h, acc[0], 0,0,0);
            acc[1] = __builtin_amdgcn_mfma_f32_32x32x16_bf16(a0l, b1h, acc[1], 0,0,0);
        }
    }

    #pragma unroll
    for (int fn = 0; fn < 2; fn++){
        int colb = col0 + wc*64 + fn*32 + lq;
        float bb = bias[colb];
        #pragma unroll
        for (int r = 0; r < 16; r++){
            int orow = row0 + wr*32 + (r&3) + 8*(r>>2) + 4*hi;
            if (orow < M_ROWS){
                int b = orow / NTOK, n = orow % NTOK;
                out[((size_t)n*NB + b)*NC + colb] = alpha*acc[fn][r] + bb;
            }
        }
    }
}

// ---------------------------------------------------------------------------
// Shared flash inner body (proven R5-R9). Q=K pointers may differ (x_ori).
// ---------------------------------------------------------------------------
__device__ __forceinline__ void flash_body(
    const unsigned short* Qh, const unsigned short* Ql,
    const unsigned short* Kh, const unsigned short* Kl,
    const unsigned short* VT,
    unsigned short* Ohi, unsigned short* Olo,
    float scale, int acc, int bh, int qt, int lane)
{
    int hi = lane >> 5, lq = lane & 31;
    const size_t base = (size_t)bh * NTOK * HD;
    const size_t vtb  = (size_t)bh * HD * VTW;

    int qrow = qt*32 + lq;
    int qr = qrow < NTOK ? qrow : NTOK-1;
    const size_t qoff = base + (size_t)qr*HD + 8*hi;
    bf16x8_t qfh[4], qfl[4];
    #pragma unroll
    for (int c = 0; c < 4; c++){
        qfh[c] = *(const bf16x8_t*)(Qh + qoff + 16*c);
        qfl[c] = *(const bf16x8_t*)(Ql + qoff + 16*c);
    }

    f32x16_t od0, od1;
    #pragma unroll
    for (int r = 0; r < 16; r++){ od0[r]=0.f; od1[r]=0.f; }
    float m_ = -1e30f, l_ = 0.f;

    for (int kt = 0; kt < 19; kt++){
        int krow = kt*32 + lq;
        int kr = krow < NTOK ? krow : NTOK-1;
        const size_t koff = base + (size_t)kr*HD + 8*hi;
        bf16x8_t kfh[4], kfl[4];
        #pragma unroll
        for (int c = 0; c < 4; c++){
            kfh[c] = *(const bf16x8_t*)(Kh + koff + 16*c);
            kfl[c] = *(const bf16x8_t*)(Kl + koff + 16*c);
        }
        f32x16_t sf;
        #pragma unroll
        for (int r = 0; r < 16; r++) sf[r] = 0.f;
        #pragma unroll
        for (int c = 0; c < 4; c++){
            sf = __builtin_amdgcn_mfma_f32_32x32x16_bf16(kfh[c], qfh[c], sf, 0,0,0);
            sf = __builtin_amdgcn_mfma_f32_32x32x16_bf16(kfh[c], qfl[c], sf, 0,0,0);
            sf = __builtin_amdgcn_mfma_f32_32x32x16_bf16(kfl[c], qfh[c], sf, 0,0,0);
        }
        float p[16];
        float tm = -1e30f;
        if (kt == 18){
            #pragma unroll
            for (int r = 0; r < 16; r++){
                int key = 576 + (r&3) + 8*(r>>2) + 4*hi;
                p[r] = (key < NTOK) ? sf[r]*scale : -1e30f;
                tm = fmaxf(tm, p[r]);
            }
        } else {
            #pragma unroll
            for (int r = 0; r < 16; r++){ p[r] = sf[r]*scale; tm = fmaxf(tm, p[r]); }
        }
        tm = fmaxf(tm, __shfl_xor(tm, 32));
        float mn = fmaxf(m_, tm);
        float corr = __expf(m_ - mn);
        float ps = 0.f;
        #pragma unroll
        for (int r = 0; r < 16; r++){ p[r] = __expf(p[r] - mn); ps += p[r]; }
        ps += __shfl_xor(ps, 32);
        l_ = l_*corr + ps;
        m_ = mn;
        #pragma unroll
        for (int r = 0; r < 16; r++){
            int crow = (r&3) + 8*(r>>2) + 4*hi;
            float cR = __shfl(corr, crow);
            od0[r] *= cR; od1[r] *= cR;
        }

        U4 pa[2];
        #pragma unroll
        for (int ks = 0; ks < 2; ks++){
            unsigned int X0 = cvt_pk(p[8*ks+0], p[8*ks+1]);
            unsigned int X1 = cvt_pk(p[8*ks+2], p[8*ks+3]);
            unsigned int X2 = cvt_pk(p[8*ks+4], p[8*ks+5]);
            unsigned int X3 = cvt_pk(p[8*ks+6], p[8*ks+7]);
            unsigned int Y0 = (unsigned int)__shfl_xor((int)X2, 32);
            unsigned int Y1 = (unsigned int)__shfl_xor((int)X3, 32);
            unsigned int Y2 = (unsigned int)__shfl_xor((int)X0, 32);
            unsigned int Y3 = (unsigned int)__shfl_xor((int)X1, 32);
            pa[ks].u[0] = hi ? Y0 : X0;
            pa[ks].u[1] = hi ? Y1 : X1;
            pa[ks].u[2] = hi ? X2 : Y2;
            pa[ks].u[3] = hi ? X3 : Y3;
        }
        const size_t v0 = vtb + (size_t)lq*VTW      + kt*32 + 8*hi;
        const size_t v1 = vtb + (size_t)(32+lq)*VTW + kt*32 + 8*hi;
        bf16x8_t vf00 = *(const bf16x8_t*)(VT + v0);
        bf16x8_t vf01 = *(const bf16x8_t*)(VT + v0 + 16);
        bf16x8_t vf10 = *(const bf16x8_t*)(VT + v1);
        bf16x8_t vf11 = *(const bf16x8_t*)(VT + v1 + 16);
        od0 = __builtin_amdgcn_mfma_f32_32x32x16_bf16(pa[0].v, vf00, od0, 0,0,0);
        od0 = __builtin_amdgcn_mfma_f32_32x32x16_bf16(pa[1].v, vf01, od0, 0,0,0);
        od1 = __builtin_amdgcn_mfma_f32_32x32x16_bf16(pa[0].v, vf10, od1, 0,0,0);
        od1 = __builtin_amdgcn_mfma_f32_32x32x16_bf16(pa[1].v, vf11, od1, 0,0,0);
    }

    float linv = 1.f / l_;
    #pragma unroll
    for (int r = 0; r < 16; r++){
        int crow = (r&3) + 8*(r>>2) + 4*hi;
        int qg = qt*32 + crow;
        float li = __shfl(linv, crow);
        if (qg < NTOK){
            size_t o0 = base + (size_t)qg*HD + lq;
            float a0 = od0[r]*li, a1 = od1[r]*li;
            if (acc){
                a0 += bf2f(Ohi[o0])    + bf2f(Olo[o0]);
                a1 += bf2f(Ohi[o0+32]) + bf2f(Olo[o0+32]);
            }
            unsigned short h0 = f2bf(a0), h1 = f2bf(a1);
            Ohi[o0] = h0;    Olo[o0]    = f2bf(a0 - bf2f(h0));
            Ohi[o0+32] = h1; Olo[o0+32] = f2bf(a1 - bf2f(h1));
        }
    }
}

__global__ __launch_bounds__(256) void flash2(
    const unsigned short* __restrict__ Qh, const unsigned short* __restrict__ Ql,
    const unsigned short* __restrict__ Kh, const unsigned short* __restrict__ Kl,
    const unsigned short* __restrict__ VT,
    unsigned short* __restrict__ Ohi, unsigned short* __restrict__ Olo,
    const float* __restrict__ itemp, float cscale, int acc)
{
    int w = threadIdx.x >> 6, lane = threadIdx.x & 63;
    int bid = blockIdx.x;
    int bh = (bid & 7) * 16 + (bid >> 3) / 5;
    int qt = ((bid >> 3) % 5) * 4 + w;
    if (qt >= 19) return;
    float scale = itemp ? itemp[bh >> 4] : cscale;
    flash_body(Qh, Ql, Kh, Kl, VT, Ohi, Olo, scale, acc, bh, qt, lane);
}

// Batched: 3 independent self-attentions (Q=K), slice = blockIdx.y.
__global__ __launch_bounds__(256) void flash2b(
    const unsigned short* __restrict__ q0h, const unsigned short* __restrict__ q0l,
    const unsigned short* __restrict__ q1h, const unsigned short* __restrict__ q1l,
    const unsigned short* __restrict__ q2h, const unsigned short* __restrict__ q2l,
    const unsigned short* __restrict__ vt0, const unsigned short* __restrict__ vt1,
    const unsigned short* __restrict__ vt2,
    unsigned short* __restrict__ o0h, unsigned short* __restrict__ o0l,
    unsigned short* __restrict__ o1h, unsigned short* __restrict__ o1l,
    unsigned short* __restrict__ o2h, unsigned short* __restrict__ o2l,
    const float* __restrict__ itemp)
{
    int w = threadIdx.x >> 6, lane = threadIdx.x & 63;
    int bid = blockIdx.x;
    int bh = (bid & 7) * 16 + (bid >> 3) / 5;
    int qt = ((bid >> 3) % 5) * 4 + w;
    if (qt >= 19) return;
    int i = blockIdx.y;
    const unsigned short *Qh, *Ql, *VT;
    unsigned short *Oh, *Ol;
    if (i == 0){ Qh=q0h; Ql=q0l; VT=vt0; Oh=o0h; Ol=o0l; }
    else if (i == 1){ Qh=q1h; Ql=q1l; VT=vt1; Oh=o1h; Ol=o1l; }
    else { Qh=q2h; Ql=q2l; VT=vt2; Oh=o2h; Ol=o2l; }
    flash_body(Qh, Ql, Qh, Ql, VT, Oh, Ol, itemp[bh >> 4], 0, bh, qt, lane);
}

// ---------------------------------------------------------------------------
// sum of 3 split-bf16 buffers -> split-bf16 (fp32 adds, fixed order)
// ---------------------------------------------------------------------------
__global__ __launch_bounds__(256) void sum3(
    const unsigned short* __restrict__ ah, const unsigned short* __restrict__ al,
    const unsigned short* __restrict__ bh, const unsigned short* __restrict__ bl,
    const unsigned short* __restrict__ ch, const unsigned short* __restrict__ cl,
    unsigned short* __restrict__ oh, unsigned short* __restrict__ ol)
{
    size_t idx = ((size_t)blockIdx.x*256 + threadIdx.x)*4;
    ushort4 vah = *(const ushort4*)(ah+idx), val = *(const ushort4*)(al+idx);
    ushort4 vbh = *(const ushort4*)(bh+idx), vbl = *(const ushort4*)(bl+idx);
    ushort4 vch = *(const ushort4*)(ch+idx), vcl = *(const ushort4*)(cl+idx);
    ushort4 rh, rl;
    #define S3(f) { \
        float s = bf2f(vah.f)+bf2f(val.f)+bf2f(vbh.f)+bf2f(vbl.f)+bf2f(vch.f)+bf2f(vcl.f); \
        rh.f = f2bf(s); rl.f = f2bf(s - bf2f(rh.f)); }
    S3(x) S3(y) S3(z) S3(w)
    #undef S3
    *(ushort4*)(oh+idx) = rh;
    *(ushort4*)(ol+idx) = rl;
}

// ---------------------------------------------------------------------------
__global__ __launch_bounds__(256) void row_norm(const float* __restrict__ X,
                                                float* __restrict__ rn)
{
    int id = blockIdx.x;
    int b = id / NTOK, n = id % NTOK;
    const float* src = X + ((size_t)n*NB + b)*NC;
    int tid = threadIdx.x;
    float s = 0.f;
    for (int i = tid; i < NC; i += 256) { float t = src[i]; s += t*t; }
    #pragma unroll
    for (int o = 1; o < 64; o <<= 1) s += __shfl_xor(s, o);
    __shared__ float red[4];
    if ((tid & 63) == 0) red[tid >> 6] = s;
    __syncthreads();
    if (tid == 0) rn[id] = sqrtf(red[0] + red[1] + red[2] + red[3]);
}

__global__ __launch_bounds__(256) void calc_invtemp(const float* __restrict__ rn,
                                                    float* __restrict__ it)
{
    int b = blockIdx.x;
    int tid = threadIdx.x;
    float s = 0.f;
    for (int i = tid; i < NTOK; i += 256) s += rn[b*NTOK + i];
    #pragma unroll
    for (int o = 1; o < 64; o <<= 1) s += __shfl_xor(s, o);
    __shared__ float red[4];
    if ((tid & 63) == 0) red[tid >> 6] = s;
    __syncthreads();
    if (tid == 0) it[b] = (red[0]+red[1]+red[2]+red[3]) / (float)NTOK * 0.125f;
}

// ---------------------------------------------------------------------------
__global__ __launch_bounds__(256) void l2n_s2s(const unsigned short* __restrict__ ih,
        const unsigned short* __restrict__ il,
        unsigned short* __restrict__ oh, unsigned short* __restrict__ ol)
{
    size_t row = (size_t)blockIdx.x*4 + (threadIdx.x >> 6);
    int lane = threadIdx.x & 63;
    size_t ii = row*HD + lane;
    float x = bf2f(ih[ii]) + bf2f(il[ii]);
    float s = x*x;
    #pragma unroll
    for (int o = 1; o < 64; o <<= 1) s += __shfl_xor(s, o);
    float xn = x / fmaxf(sqrtf(s), 1e-12f);
    unsigned short hv = f2bf(xn);
    oh[ii] = hv;
    ol[ii] = f2bf(xn - bf2f(hv));
}

// ---------------------------------------------------------------------------
extern "C" void kernel_launch(void* const* d_in, const int* in_sizes, int n_in,
                              void* d_out, int out_size, void* d_ws, size_t ws_size,
                              hipStream_t stream)
{
    const float* x      = (const float*)d_in[0];
    const float* qkv_w  = (const float*)d_in[1];
    const float* qkv_b  = (const float*)d_in[2];
    const float* proj_w = (const float*)d_in[3];
    const float* proj_b = (const float*)d_in[4];
    float* out = (float*)d_out;            // [0,SZ)=x_gem, [SZ,2SZ)=x_ori

    unsigned short* w16 = (unsigned short*)d_ws;
    #define SL(i) (w16 + (size_t)(i)*SZ)          // 8 bf16 slots
    // common region after slots:
    unsigned short* WQh = w16 + 8*SZ;             // [8SZ, 8SZ+2WSZ): WQ, dead after qkv
    unsigned short* WQl = WQh + WSZ;
    unsigned short* VT1 = WQh;                    // aliases WQ (created later)
    size_t p = 8*SZ + 2*WSZ;
    unsigned short* VTv = w16 + p;  p += VTSZ;
    unsigned short* VT2 = w16 + p;  p += VTSZ;    // batched-only
    unsigned short* VT3 = w16 + p;  p += VTSZ;    // batched-only
    unsigned short* WPh = w16 + p;  p += PSZ;
    unsigned short* WPl = w16 + p;  p += PSZ;
    unsigned short* E0  = w16 + p;  p += SZ;      // batched-only extra pair
    unsigned short* E1  = w16 + p;  p += SZ;
    float* rn = (float*)(w16 + p);
    float* it = rn + M_ROWS;
    size_t need = (p + 2*(M_ROWS + 8)) * sizeof(unsigned short);
    // serial-path need (R9 layout, proven): everything up through WP + rn
    int batched = (ws_size >= need);

    unsigned short* S0 = (unsigned short*)d_out;  // x_gem bytes (scratch pair)
    unsigned short* S1 = S0 + SZ;

    dim3 blk(256);
    dim3 gq(24,37), gp(8,73), gfl(640), gflb(640,3), gt(10,128);

    // common prologue
    row_norm<<<dim3(M_ROWS), blk, 0, stream>>>(x, rn);
    calc_invtemp<<<dim3(NB), blk, 0, stream>>>(rn, it);
    split_rows<<<dim3(M_ROWS), blk, 0, stream>>>(x, SL(6), SL(7), 1);
    split_rows<<<dim3(3*NC),  blk, 0, stream>>>(qkv_w, WQh, WQl, 0);
    gemm_qkv_mfma<<<gq, blk, 0, stream>>>(SL(6), SL(7), WQh, WQl, qkv_b,
        SL(0), SL(1), SL(2), SL(3), SL(4), SL(5));
    transp64<<<gt, blk, 0, stream>>>(SL(4), VTv);
    // x_ori = proj(softmax(q k^T/8) v)
    flash2<<<gfl, blk, 0, stream>>>(SL(0),SL(1),SL(2),SL(3), VTv,
        SL(6),SL(7), nullptr, 0.125f, 0);
    split_rows<<<dim3(NC), blk, 0, stream>>>(proj_w, WPh, WPl, 0);
    gemm_proj_mfma<<<gp, blk, 0, stream>>>(SL(6),SL(7), WPh,WPl, proj_b, 1.f,
        out + SZ);

    if (batched){
        // xs_i = l2n in-place on v(4,5), k(2,3), q(0,1); transposes (WQ dead)
        l2n_s2s<<<dim3(18464), blk, 0, stream>>>(SL(4),SL(5), SL(4),SL(5));
        l2n_s2s<<<dim3(18464), blk, 0, stream>>>(SL(2),SL(3), SL(2),SL(3));
        l2n_s2s<<<dim3(18464), blk, 0, stream>>>(SL(0),SL(1), SL(0),SL(1));
        transp64<<<gt, blk, 0, stream>>>(SL(4), VT1);
        transp64<<<gt, blk, 0, stream>>>(SL(2), VT2);
        transp64<<<gt, blk, 0, stream>>>(SL(0), VT3);
        // ys_i concurrently: outputs (6,7), S-pair, E-pair
        flash2b<<<gflb, blk, 0, stream>>>(
            SL(4),SL(5), SL(2),SL(3), SL(0),SL(1),
            VT1, VT2, VT3,
            SL(6),SL(7), S0,S1, E0,E1, it);
        // z_i = l2n in-place
        l2n_s2s<<<dim3(18464), blk, 0, stream>>>(SL(6),SL(7), SL(6),SL(7));
        l2n_s2s<<<dim3(18464), blk, 0, stream>>>(S0,S1, S0,S1);
        l2n_s2s<<<dim3(18464), blk, 0, stream>>>(E0,E1, E0,E1);
        // final attentions concurrently (V = original v via VTv)
        flash2b<<<gflb, blk, 0, stream>>>(
            SL(6),SL(7), S0,S1, E0,E1,
            VTv, VTv, VTv,
            SL(4),SL(5), SL(2),SL(3), SL(0),SL(1), it);
        sum3<<<dim3(4616), blk, 0, stream>>>(
            SL(4),SL(5), SL(2),SL(3), SL(0),SL(1), SL(4),SL(5));
        gemm_proj_mfma<<<gp, blk, 0, stream>>>(SL(4),SL(5), WPh,WPl, proj_b,
            1.f/3.f, out);
    } else {
        // proven serial fallback (R9-style with flash2-acc final stage)
        unsigned short* VTx = WQh;                // reuse WQ region
        // xs1 = l2n(v) -> (6,7); ys1 -> (4,5); z1 -> (6,7)
        l2n_s2s<<<dim3(18464), blk, 0, stream>>>(SL(4),SL(5), SL(6),SL(7));
        transp64<<<gt, blk, 0, stream>>>(SL(6), VTx);
        flash2<<<gfl, blk, 0, stream>>>(SL(6),SL(7),SL(6),SL(7), VTx,
            SL(4),SL(5), it, 0.f, 0);
        l2n_s2s<<<dim3(18464), blk, 0, stream>>>(SL(4),SL(5), SL(6),SL(7));
        // xs2 = l2n(k) in-place; ys2 -> (4,5); z2 -> (2,3)
        l2n_s2s<<<dim3(18464), blk, 0, stream>>>(SL(2),SL(3), SL(2),SL(3));
        transp64<<<gt, blk, 0, stream>>>(SL(2), VTx);
        flash2<<<gfl, blk, 0, stream>>>(SL(2),SL(3),SL(2),SL(3), VTx,
            SL(4),SL(5), it, 0.f, 0);
        l2n_s2s<<<dim3(18464), blk, 0, stream>>>(SL(4),SL(5), SL(2),SL(3));
        // xs3 = l2n(q) in-place; ys3 -> (4,5); z3 -> (0,1)
        l2n_s2s<<<dim3(18464), blk, 0, stream>>>(SL(0),SL(1), SL(0),SL(1));
        transp64<<<gt, blk, 0, stream>>>(SL(0), VTx);
        flash2<<<gfl, blk, 0, stream>>>(SL(0),SL(1),SL(0),SL(1), VTx,
            SL(4),SL(5), it, 0.f, 0);
        l2n_s2s<<<dim3(18464), blk, 0, stream>>>(SL(4),SL(5), SL(0),SL(1));
        // accumulate final three
        flash2<<<gfl, blk, 0, stream>>>(SL(6),SL(7),SL(6),SL(7), VTv,
            SL(4),SL(5), it, 0.f, 0);
        flash2<<<gfl, blk, 0, stream>>>(SL(2),SL(3),SL(2),SL(3), VTv,
            SL(4),SL(5), it, 0.f, 1);
        flash2<<<gfl, blk, 0, stream>>>(SL(0),SL(1),SL(0),SL(1), VTv,
            SL(4),SL(5), it, 0.f, 1);
        gemm_proj_mfma<<<gp, blk, 0, stream>>>(SL(4),SL(5), WPh,WPl, proj_b,
            1.f/3.f, out);
    }
    #undef SL
}

// Round 11
// 752.794 us; speedup vs baseline: 1.6873x; 1.0543x over previous
//
#include <hip/hip_runtime.h>
#include <math.h>

#define NTOK 577
#define NB 8
#define NC 1024
#define NH 16
#define HD 64
#define M_ROWS (NB*NTOK)               // 4616
#define SZ ((size_t)NB*NH*NTOK*HD)     // 4726784 elements
#define WSZ ((size_t)3*NC*NC)          // 3145728
#define PSZ ((size_t)NC*NC)            // 1048576
#define VTW 608                        // padded key width for VT (19*32)
#define VTSZ ((size_t)NB*NH*HD*VTW)    // 4980736
#define HSTR ((size_t)NTOK*HD)         // 36928 head stride in A-layout
#define LP 36                          // padded LDS row (32 data + 4 pad)

typedef __attribute__((ext_vector_type(8)))  short bf16x8_t;
typedef __attribute__((ext_vector_type(8)))  unsigned short u16x8_t;
typedef __attribute__((ext_vector_type(16))) float f32x16_t;

union U4 { unsigned short s[8]; unsigned int u[4]; bf16x8_t v; };

__device__ inline unsigned short f2bf(float x){
    unsigned int u = __float_as_uint(x);
    u = (u + 0x7FFFu + ((u>>16)&1u)) >> 16;
    return (unsigned short)u;
}
__device__ inline float bf2f(unsigned short h){
    return __uint_as_float(((unsigned int)h)<<16);
}
__device__ inline unsigned int cvt_pk(float a, float b){
    unsigned int r;
    asm volatile("v_cvt_pk_bf16_f32 %0, %1, %2" : "=v"(r) : "v"(a), "v"(b));
    return r;
}

// ---------------------------------------------------------------------------
// split fp32 rows -> bf16 hi/lo [nrows][1024]. mode 0: row-major src.
// mode 1: X [N,B,C] gather (row m=b*577+n -> src row n*8+b).
// ---------------------------------------------------------------------------
__global__ __launch_bounds__(256) void split_rows(const float* __restrict__ src,
        unsigned short* __restrict__ dh, unsigned short* __restrict__ dl, int mode)
{
    int row = blockIdx.x, t = threadIdx.x;
    const float* s;
    if (mode == 0) s = src + (size_t)row*NC + 4*t;
    else {
        int b = row / NTOK, n = row % NTOK;
        s = src + ((size_t)n*NB + b)*NC + 4*t;
    }
    float4 v = *(const float4*)s;
    ushort4 hv, lv;
    hv.x = f2bf(v.x); lv.x = f2bf(v.x - bf2f(hv.x));
    hv.y = f2bf(v.y); lv.y = f2bf(v.y - bf2f(hv.y));
    hv.z = f2bf(v.z); lv.z = f2bf(v.z - bf2f(hv.z));
    hv.w = f2bf(v.w); lv.w = f2bf(v.w - bf2f(hv.w));
    *(ushort4*)(dh + (size_t)row*NC + 4*t) = hv;
    *(ushort4*)(dl + (size_t)row*NC + 4*t) = lv;
}

// ---------------------------------------------------------------------------
// Coalesced transpose: src hi-bf16 [BH][577][64] -> dst [BH][64][608], pads=0.
// ---------------------------------------------------------------------------
__global__ __launch_bounds__(256) void transp64(const unsigned short* __restrict__ src,
                                                unsigned short* __restrict__ dst)
{
    __shared__ unsigned short t[64][72];
    int bh = blockIdx.y;
    int n0 = blockIdx.x * 64;
    int tid = threadIdx.x;
    int r  = tid >> 2;
    int c0 = (tid & 3) * 16;
    int n = n0 + r;
    if (n < NTOK){
        const unsigned short* s = src + ((size_t)bh*NTOK + n)*HD + c0;
        *(u16x8_t*)&t[r][c0]   = *(const u16x8_t*)s;
        *(u16x8_t*)&t[r][c0+8] = *(const u16x8_t*)(s + 8);
    } else {
        u16x8_t z = (u16x8_t)0;
        *(u16x8_t*)&t[r][c0]   = z;
        *(u16x8_t*)&t[r][c0+8] = z;
    }
    __syncthreads();
    if (n0 + c0 < VTW){
        int d = r;
        U4 o0, o1;
        #pragma unroll
        for (int j = 0; j < 8; j++){ o0.s[j] = t[c0+j][d]; o1.s[j] = t[c0+8+j][d]; }
        unsigned short* dp = dst + ((size_t)bh*HD + d)*VTW + n0 + c0;
        *(u16x8_t*)dp       = (u16x8_t)o0.v;
        *(u16x8_t*)(dp + 8) = (u16x8_t)o1.v;
    }
}

#define MFMA12(a0h,a1h,b0h,b1h,a0l,a1l,b0l,b1l) \
    acc[0][0] = __builtin_amdgcn_mfma_f32_32x32x16_bf16(a0h, b0h, acc[0][0], 0,0,0); \
    acc[0][1] = __builtin_amdgcn_mfma_f32_32x32x16_bf16(a0h, b1h, acc[0][1], 0,0,0); \
    acc[1][0] = __builtin_amdgcn_mfma_f32_32x32x16_bf16(a1h, b0h, acc[1][0], 0,0,0); \
    acc[1][1] = __builtin_amdgcn_mfma_f32_32x32x16_bf16(a1h, b1h, acc[1][1], 0,0,0); \
    acc[0][0] = __builtin_amdgcn_mfma_f32_32x32x16_bf16(a0h, b0l, acc[0][0], 0,0,0); \
    acc[0][1] = __builtin_amdgcn_mfma_f32_32x32x16_bf16(a0h, b1l, acc[0][1], 0,0,0); \
    acc[1][0] = __builtin_amdgcn_mfma_f32_32x32x16_bf16(a1h, b0l, acc[1][0], 0,0,0); \
    acc[1][1] = __builtin_amdgcn_mfma_f32_32x32x16_bf16(a1h, b1l, acc[1][1], 0,0,0); \
    acc[0][0] = __builtin_amdgcn_mfma_f32_32x32x16_bf16(a0l, b0h, acc[0][0], 0,0,0); \
    acc[0][1] = __builtin_amdgcn_mfma_f32_32x32x16_bf16(a0l, b1h, acc[0][1], 0,0,0); \
    acc[1][0] = __builtin_amdgcn_mfma_f32_32x32x16_bf16(a1l, b0h, acc[1][0], 0,0,0); \
    acc[1][1] = __builtin_amdgcn_mfma_f32_32x32x16_bf16(a1l, b1h, acc[1][1], 0,0,0);

// ---------------------------------------------------------------------------
// qkv GEMM, LDS-staged (128x128 tile, BK=32, padded LDS rows, 4 waves 2x2).
// ---------------------------------------------------------------------------
__global__ __launch_bounds__(256) void gemm_qkv_mfma(
    const unsigned short* __restrict__ Ah, const unsigned short* __restrict__ Al,
    const unsigned short* __restrict__ Bh, const unsigned short* __restrict__ Bl,
    const float* __restrict__ bias,
    unsigned short* __restrict__ qh, unsigned short* __restrict__ ql,
    unsigned short* __restrict__ kh, unsigned short* __restrict__ kl,
    unsigned short* __restrict__ vh, unsigned short* __restrict__ vl)
{
    __shared__ unsigned short ahs[128][LP], als[128][LP];
    __shared__ unsigned short bhs[128][LP], bls[128][LP];
    int t = threadIdx.x;
    int l = t & 63, w = t >> 6;
    int lq = l & 31, hi = l >> 5;
    int wr = w >> 1, wc = w & 1;
    int col0 = blockIdx.x*128, row0 = blockIdx.y*128;

    int srow[2], scol[2], sa[2];
    #pragma unroll
    for (int i = 0; i < 2; i++){
        int idx = i*256 + t;
        srow[i] = idx >> 2;
        scol[i] = (idx & 3) * 8;
        int ar = row0 + srow[i]; if (ar >= M_ROWS) ar = M_ROWS-1;
        sa[i] = ar;
    }

    f32x16_t acc[2][2];
    #pragma unroll
    for (int i = 0; i < 16; i++){
        acc[0][0][i]=0.f; acc[0][1][i]=0.f; acc[1][0][i]=0.f; acc[1][1][i]=0.f;
    }

    for (int k0 = 0; k0 < NC; k0 += 32){
        if (k0) __syncthreads();
        #pragma unroll
        for (int i = 0; i < 2; i++){
            size_t ao = (size_t)sa[i]*NC + k0 + scol[i];
            size_t bo = (size_t)(col0 + srow[i])*NC + k0 + scol[i];
            u16x8_t va  = *(const u16x8_t*)(Ah + ao);
            u16x8_t va2 = *(const u16x8_t*)(Al + ao);
            u16x8_t vb  = *(const u16x8_t*)(Bh + bo);
            u16x8_t vb2 = *(const u16x8_t*)(Bl + bo);
            *(u16x8_t*)&ahs[srow[i]][scol[i]] = va;
            *(u16x8_t*)&als[srow[i]][scol[i]] = va2;
            *(u16x8_t*)&bhs[srow[i]][scol[i]] = vb;
            *(u16x8_t*)&bls[srow[i]][scol[i]] = vb2;
        }
        __syncthreads();
        #pragma unroll
        for (int kk = 0; kk < 2; kk++){
            int co = kk*16 + 8*hi;
            bf16x8_t a0h = *(const bf16x8_t*)&ahs[wr*64+lq][co];
            bf16x8_t a1h = *(const bf16x8_t*)&ahs[wr*64+32+lq][co];
            bf16x8_t b0h = *(const bf16x8_t*)&bhs[wc*64+lq][co];
            bf16x8_t b1h = *(const bf16x8_t*)&bhs[wc*64+32+lq][co];
            bf16x8_t a0l = *(const bf16x8_t*)&als[wr*64+lq][co];
            bf16x8_t a1l = *(const bf16x8_t*)&als[wr*64+32+lq][co];
            bf16x8_t b0l = *(const bf16x8_t*)&bls[wc*64+lq][co];
            bf16x8_t b1l = *(const bf16x8_t*)&bls[wc*64+32+lq][co];
            MFMA12(a0h,a1h,b0h,b1h,a0l,a1l,b0l,b1l)
        }
    }

    int colW = col0 + wc*64, rowW = row0 + wr*64;
    #pragma unroll
    for (int fn = 0; fn < 2; fn++){
        int colb = colW + fn*32 + lq;
        float bb = bias[colb];
        int tt = colb >> 10, h = (colb >> 6) & 15, d = colb & 63;
        unsigned short* dsth = (tt == 0) ? qh : (tt == 1 ? kh : vh);
        unsigned short* dstl = (tt == 0) ? ql : (tt == 1 ? kl : vl);
        #pragma unroll
        for (int fm = 0; fm < 2; fm++){
            #pragma unroll
            for (int r = 0; r < 16; r++){
                int orow = rowW + fm*32 + (r&3) + 8*(r>>2) + 4*hi;
                if (orow < M_ROWS){
                    float val = acc[fm][fn][r] + bb;
                    int b = orow / NTOK, n = orow % NTOK;
                    unsigned short hv = f2bf(val);
                    unsigned short lv = f2bf(val - bf2f(hv));
                    size_t idx = ((size_t)(b*NH + h)*NTOK + n)*HD + d;
                    dsth[idx] = hv; dstl[idx] = lv;
                }
            }
        }
    }
}

// ---------------------------------------------------------------------------
// proj GEMM, LDS-staged (64x128 tile, BK=32). A split bf16 in HEAD layout.
// ---------------------------------------------------------------------------
__global__ __launch_bounds__(256) void gemm_proj_mfma(
    const unsigned short* __restrict__ Ah, const unsigned short* __restrict__ Al,
    const unsigned short* __restrict__ Bh, const unsigned short* __restrict__ Bl,
    const float* __restrict__ bias, float alpha, float* __restrict__ out)
{
    __shared__ unsigned short ahs[64][LP], als[64][LP];
    __shared__ unsigned short bhs[128][LP], bls[128][LP];
    int t = threadIdx.x;
    int l = t & 63, w = t >> 6;
    int lq = l & 31, hi = l >> 5;
    int wr = w >> 1, wc = w & 1;
    int col0 = blockIdx.x*128, row0 = blockIdx.y*64;

    int sarow = t >> 2, sacol = (t & 3) * 8;
    int ar = row0 + sarow; if (ar >= M_ROWS) ar = M_ROWS-1;
    size_t abase = (size_t)(ar / NTOK)*NH*HSTR + (size_t)(ar % NTOK)*HD;
    int sbrow[2], sbcol[2];
    #pragma unroll
    for (int i = 0; i < 2; i++){
        int idx = i*256 + t;
        sbrow[i] = idx >> 2;
        sbcol[i] = (idx & 3) * 8;
    }

    f32x16_t acc[2];
    #pragma unroll
    for (int i = 0; i < 16; i++){ acc[0][i]=0.f; acc[1][i]=0.f; }

    for (int k0 = 0; k0 < NC; k0 += 32){
        if (k0) __syncthreads();
        {
            int kk = k0 + sacol;
            size_t ao = abase + (size_t)(kk >> 6)*HSTR + (kk & 63);
            u16x8_t va  = *(const u16x8_t*)(Ah + ao);
            u16x8_t va2 = *(const u16x8_t*)(Al + ao);
            *(u16x8_t*)&ahs[sarow][sacol] = va;
            *(u16x8_t*)&als[sarow][sacol] = va2;
            #pragma unroll
            for (int i = 0; i < 2; i++){
                size_t bo = (size_t)(col0 + sbrow[i])*NC + k0 + sbcol[i];
                u16x8_t vb  = *(const u16x8_t*)(Bh + bo);
                u16x8_t vb2 = *(const u16x8_t*)(Bl + bo);
                *(u16x8_t*)&bhs[sbrow[i]][sbcol[i]] = vb;
                *(u16x8_t*)&bls[sbrow[i]][sbcol[i]] = vb2;
            }
        }
        __syncthreads();
        #pragma unroll
        for (int kk = 0; kk < 2; kk++){
            int co = kk*16 + 8*hi;
            bf16x8_t a0h = *(const bf16x8_t*)&ahs[wr*32+lq][co];
            bf16x8_t a0l = *(const bf16x8_t*)&als[wr*32+lq][co];
            bf16x8_t b0h = *(const bf16x8_t*)&bhs[wc*64+lq][co];
            bf16x8_t b1h = *(const bf16x8_t*)&bhs[wc*64+32+lq][co];
            bf16x8_t b0l = *(const bf16x8_t*)&bls[wc*64+lq][co];
            bf16x8_t b1l = *(const bf16x8_t*)&bls[wc*64+32+lq][co];
            acc[0] = __builtin_amdgcn_mfma_f32_32x32x16_bf16(a0h, b0h, acc[0], 0,0,0);
            acc[1] = __builtin_amdgcn_mfma_f32_32x32x16_bf16(a0h, b1h, acc[1], 0,0,0);
            acc[0] = __builtin_amdgcn_mfma_f32_32x32x16_bf16(a0h, b0l, acc[0], 0,0,0);
            acc[1] = __builtin_amdgcn_mfma_f32_32x32x16_bf16(a0h, b1l, acc[1], 0,0,0);
            acc[0] = __builtin_amdgcn_mfma_f32_32x32x16_bf16(a0l, b0h, acc[0], 0,0,0);
            acc[1] = __builtin_amdgcn_mfma_f32_32x32x16_bf16(a0l, b1h, acc[1], 0,0,0);
        }
    }

    #pragma unroll
    for (int fn = 0; fn < 2; fn++){
        int colb = col0 + wc*64 + fn*32 + lq;
        float bb = bias[colb];
        #pragma unroll
        for (int r = 0; r < 16; r++){
            int orow = row0 + wr*32 + (r&3) + 8*(r>>2) + 4*hi;
            if (orow < M_ROWS){
                int b = orow / NTOK, n = orow % NTOK;
                out[((size_t)n*NB + b)*NC + colb] = alpha*acc[fn][r] + bb;
            }
        }
    }
}

// ---------------------------------------------------------------------------
// Flash inner body. VAR=0: online softmax + 1/l (proven R5-R10; x_ori).
// VAR=1: static max (=scale, exact for l2n'd Q=K self-attn: diagonal is the
//        row max) + fused output-l2n (1/l cancels inside l2n) - ys->z pass.
// VAR=2: static max + 1/l (final attention passes).
// ---------------------------------------------------------------------------
template<int VAR>
__device__ __forceinline__ void flash_body(
    const unsigned short* Qh, const unsigned short* Ql,
    const unsigned short* Kh, const unsigned short* Kl,
    const unsigned short* VT,
    unsigned short* Ohi, unsigned short* Olo,
    float scale, int acc, int bh, int qt, int lane)
{
    int hi = lane >> 5, lq = lane & 31;
    const size_t base = (size_t)bh * NTOK * HD;
    const size_t vtb  = (size_t)bh * HD * VTW;

    int qrow = qt*32 + lq;
    int qr = qrow < NTOK ? qrow : NTOK-1;
    const size_t qoff = base + (size_t)qr*HD + 8*hi;
    bf16x8_t qfh[4], qfl[4];
    #pragma unroll
    for (int c = 0; c < 4; c++){
        qfh[c] = *(const bf16x8_t*)(Qh + qoff + 16*c);
        qfl[c] = *(const bf16x8_t*)(Ql + qoff + 16*c);
    }

    f32x16_t od0, od1;
    #pragma unroll
    for (int r = 0; r < 16; r++){ od0[r]=0.f; od1[r]=0.f; }
    float m_ = -1e30f, l_ = 0.f;

    for (int kt = 0; kt < 19; kt++){
        int krow = kt*32 + lq;
        int kr = krow < NTOK ? krow : NTOK-1;
        const size_t koff = base + (size_t)kr*HD + 8*hi;
        bf16x8_t kfh[4], kfl[4];
        #pragma unroll
        for (int c = 0; c < 4; c++){
            kfh[c] = *(const bf16x8_t*)(Kh + koff + 16*c);
            kfl[c] = *(const bf16x8_t*)(Kl + koff + 16*c);
        }
        f32x16_t sf;
        #pragma unroll
        for (int r = 0; r < 16; r++) sf[r] = 0.f;
        __builtin_amdgcn_s_setprio(1);
        #pragma unroll
        for (int c = 0; c < 4; c++){
            sf = __builtin_amdgcn_mfma_f32_32x32x16_bf16(kfh[c], qfh[c], sf, 0,0,0);
            sf = __builtin_amdgcn_mfma_f32_32x32x16_bf16(kfh[c], qfl[c], sf, 0,0,0);
            sf = __builtin_amdgcn_mfma_f32_32x32x16_bf16(kfl[c], qfh[c], sf, 0,0,0);
        }
        __builtin_amdgcn_s_setprio(0);

        float p[16];
        if (VAR == 0){
            float tm = -1e30f;
            if (kt == 18){
                #pragma unroll
                for (int r = 0; r < 16; r++){
                    int key = 576 + (r&3) + 8*(r>>2) + 4*hi;
                    p[r] = (key < NTOK) ? sf[r]*scale : -1e30f;
                    tm = fmaxf(tm, p[r]);
                }
            } else {
                #pragma unroll
                for (int r = 0; r < 16; r++){ p[r] = sf[r]*scale; tm = fmaxf(tm, p[r]); }
            }
            tm = fmaxf(tm, __shfl_xor(tm, 32));
            float mn = fmaxf(m_, tm);
            float corr = __expf(m_ - mn);
            float ps = 0.f;
            #pragma unroll
            for (int r = 0; r < 16; r++){ p[r] = __expf(p[r] - mn); ps += p[r]; }
            ps += __shfl_xor(ps, 32);
            l_ = l_*corr + ps;
            m_ = mn;
            #pragma unroll
            for (int r = 0; r < 16; r++){
                int crow = (r&3) + 8*(r>>2) + 4*hi;
                float cR = __shfl(corr, crow);
                od0[r] *= cR; od1[r] *= cR;
            }
        } else {
            // static max == scale (row max is the diagonal, exactly scale)
            if (kt == 18){
                #pragma unroll
                for (int r = 0; r < 16; r++){
                    int key = 576 + (r&3) + 8*(r>>2) + 4*hi;
                    p[r] = (key < NTOK) ? __expf(sf[r]*scale - scale) : 0.f;
                }
            } else {
                #pragma unroll
                for (int r = 0; r < 16; r++) p[r] = __expf(sf[r]*scale - scale);
            }
            if (VAR == 2){
                #pragma unroll
                for (int r = 0; r < 16; r++) l_ += p[r];
            }
        }

        U4 pa[2];
        #pragma unroll
        for (int ks = 0; ks < 2; ks++){
            unsigned int X0 = cvt_pk(p[8*ks+0], p[8*ks+1]);
            unsigned int X1 = cvt_pk(p[8*ks+2], p[8*ks+3]);
            unsigned int X2 = cvt_pk(p[8*ks+4], p[8*ks+5]);
            unsigned int X3 = cvt_pk(p[8*ks+6], p[8*ks+7]);
            unsigned int Y0 = (unsigned int)__shfl_xor((int)X2, 32);
            unsigned int Y1 = (unsigned int)__shfl_xor((int)X3, 32);
            unsigned int Y2 = (unsigned int)__shfl_xor((int)X0, 32);
            unsigned int Y3 = (unsigned int)__shfl_xor((int)X1, 32);
            pa[ks].u[0] = hi ? Y0 : X0;
            pa[ks].u[1] = hi ? Y1 : X1;
            pa[ks].u[2] = hi ? X2 : Y2;
            pa[ks].u[3] = hi ? X3 : Y3;
        }
        const size_t v0 = vtb + (size_t)lq*VTW      + kt*32 + 8*hi;
        const size_t v1 = vtb + (size_t)(32+lq)*VTW + kt*32 + 8*hi;
        bf16x8_t vf00 = *(const bf16x8_t*)(VT + v0);
        bf16x8_t vf01 = *(const bf16x8_t*)(VT + v0 + 16);
        bf16x8_t vf10 = *(const bf16x8_t*)(VT + v1);
        bf16x8_t vf11 = *(const bf16x8_t*)(VT + v1 + 16);
        __builtin_amdgcn_s_setprio(1);
        od0 = __builtin_amdgcn_mfma_f32_32x32x16_bf16(pa[0].v, vf00, od0, 0,0,0);
        od0 = __builtin_amdgcn_mfma_f32_32x32x16_bf16(pa[1].v, vf01, od0, 0,0,0);
        od1 = __builtin_amdgcn_mfma_f32_32x32x16_bf16(pa[0].v, vf10, od1, 0,0,0);
        od1 = __builtin_amdgcn_mfma_f32_32x32x16_bf16(pa[1].v, vf11, od1, 0,0,0);
        __builtin_amdgcn_s_setprio(0);
    }

    if (VAR == 1){
        // fused l2n: z = od/||od|| per row (1/l cancels). Row crow lives in
        // the 32 lanes of this hi-half: od0 = cols 0-31, od1 = cols 32-63.
        #pragma unroll
        for (int r = 0; r < 16; r++){
            float s = od0[r]*od0[r] + od1[r]*od1[r];
            #pragma unroll
            for (int o = 1; o < 32; o <<= 1) s += __shfl_xor(s, o);
            int crow = (r&3) + 8*(r>>2) + 4*hi;
            int qg = qt*32 + crow;
            if (qg < NTOK){
                float inv = 1.f / fmaxf(sqrtf(s), 1e-12f);
                size_t o0 = base + (size_t)qg*HD + lq;
                float a0 = od0[r]*inv, a1 = od1[r]*inv;
                unsigned short h0 = f2bf(a0), h1 = f2bf(a1);
                Ohi[o0] = h0;    Olo[o0]    = f2bf(a0 - bf2f(h0));
                Ohi[o0+32] = h1; Olo[o0+32] = f2bf(a1 - bf2f(h1));
            }
        }
        return;
    }

    if (VAR == 2) l_ = l_ + __shfl_xor(l_, 32);
    float linv = 1.f / l_;
    #pragma unroll
    for (int r = 0; r < 16; r++){
        int crow = (r&3) + 8*(r>>2) + 4*hi;
        int qg = qt*32 + crow;
        float li = __shfl(linv, crow);
        if (qg < NTOK){
            size_t o0 = base + (size_t)qg*HD + lq;
            float a0 = od0[r]*li, a1 = od1[r]*li;
            if (acc){
                a0 += bf2f(Ohi[o0])    + bf2f(Olo[o0]);
                a1 += bf2f(Ohi[o0+32]) + bf2f(Olo[o0+32]);
            }
            unsigned short h0 = f2bf(a0), h1 = f2bf(a1);
            Ohi[o0] = h0;    Olo[o0]    = f2bf(a0 - bf2f(h0));
            Ohi[o0+32] = h1; Olo[o0+32] = f2bf(a1 - bf2f(h1));
        }
    }
}

__global__ __launch_bounds__(256) void flash2(
    const unsigned short* __restrict__ Qh, const unsigned short* __restrict__ Ql,
    const unsigned short* __restrict__ Kh, const unsigned short* __restrict__ Kl,
    const unsigned short* __restrict__ VT,
    unsigned short* __restrict__ Ohi, unsigned short* __restrict__ Olo,
    const float* __restrict__ itemp, float cscale, int acc)
{
    int w = threadIdx.x >> 6, lane = threadIdx.x & 63;
    int bid = blockIdx.x;
    int bh = (bid & 7) * 16 + (bid >> 3) / 5;
    int qt = ((bid >> 3) % 5) * 4 + w;
    if (qt >= 19) return;
    float scale = itemp ? itemp[bh >> 4] : cscale;
    flash_body<0>(Qh, Ql, Kh, Kl, VT, Ohi, Olo, scale, acc, bh, qt, lane);
}

// Batched: 3 independent self-attentions (Q=K), slice = blockIdx.y.
template<int VAR>
__global__ __launch_bounds__(256) void flash2b(
    const unsigned short* __restrict__ q0h, const unsigned short* __restrict__ q0l,
    const unsigned short* __restrict__ q1h, const unsigned short* __restrict__ q1l,
    const unsigned short* __restrict__ q2h, const unsigned short* __restrict__ q2l,
    const unsigned short* __restrict__ vt0, const unsigned short* __restrict__ vt1,
    const unsigned short* __restrict__ vt2,
    unsigned short* __restrict__ o0h, unsigned short* __restrict__ o0l,
    unsigned short* __restrict__ o1h, unsigned short* __restrict__ o1l,
    unsigned short* __restrict__ o2h, unsigned short* __restrict__ o2l,
    const float* __restrict__ itemp)
{
    int w = threadIdx.x >> 6, lane = threadIdx.x & 63;
    int bid = blockIdx.x;
    int bh = (bid & 7) * 16 + (bid >> 3) / 5;
    int qt = ((bid >> 3) % 5) * 4 + w;
    if (qt >= 19) return;
    int i = blockIdx.y;
    const unsigned short *Qh, *Ql, *VT;
    unsigned short *Oh, *Ol;
    if (i == 0){ Qh=q0h; Ql=q0l; VT=vt0; Oh=o0h; Ol=o0l; }
    else if (i == 1){ Qh=q1h; Ql=q1l; VT=vt1; Oh=o1h; Ol=o1l; }
    else { Qh=q2h; Ql=q2l; VT=vt2; Oh=o2h; Ol=o2l; }
    flash_body<VAR>(Qh, Ql, Qh, Ql, VT, Oh, Ol, itemp[bh >> 4], 0, bh, qt, lane);
}

// ---------------------------------------------------------------------------
// sum of 3 split-bf16 buffers -> split-bf16 (fp32 adds, fixed order)
// ---------------------------------------------------------------------------
__global__ __launch_bounds__(256) void sum3(
    const unsigned short* __restrict__ ah, const unsigned short* __restrict__ al,
    const unsigned short* __restrict__ bh, const unsigned short* __restrict__ bl,
    const unsigned short* __restrict__ ch, const unsigned short* __restrict__ cl,
    unsigned short* __restrict__ oh, unsigned short* __restrict__ ol)
{
    size_t idx = ((size_t)blockIdx.x*256 + threadIdx.x)*4;
    ushort4 vah = *(const ushort4*)(ah+idx), val = *(const ushort4*)(al+idx);
    ushort4 vbh = *(const ushort4*)(bh+idx), vbl = *(const ushort4*)(bl+idx);
    ushort4 vch = *(const ushort4*)(ch+idx), vcl = *(const ushort4*)(cl+idx);
    ushort4 rh, rl;
    #define S3(f) { \
        float s = bf2f(vah.f)+bf2f(val.f)+bf2f(vbh.f)+bf2f(vbl.f)+bf2f(vch.f)+bf2f(vcl.f); \
        rh.f = f2bf(s); rl.f = f2bf(s - bf2f(rh.f)); }
    S3(x) S3(y) S3(z) S3(w)
    #undef S3
    *(ushort4*)(oh+idx) = rh;
    *(ushort4*)(ol+idx) = rl;
}

// ---------------------------------------------------------------------------
__global__ __launch_bounds__(256) void row_norm(const float* __restrict__ X,
                                                float* __restrict__ rn)
{
    int id = blockIdx.x;
    int b = id / NTOK, n = id % NTOK;
    const float* src = X + ((size_t)n*NB + b)*NC;
    int tid = threadIdx.x;
    float s = 0.f;
    for (int i = tid; i < NC; i += 256) { float t = src[i]; s += t*t; }
    #pragma unroll
    for (int o = 1; o < 64; o <<= 1) s += __shfl_xor(s, o);
    __shared__ float red[4];
    if ((tid & 63) == 0) red[tid >> 6] = s;
    __syncthreads();
    if (tid == 0) rn[id] = sqrtf(red[0] + red[1] + red[2] + red[3]);
}

__global__ __launch_bounds__(256) void calc_invtemp(const float* __restrict__ rn,
                                                    float* __restrict__ it)
{
    int b = blockIdx.x;
    int tid = threadIdx.x;
    float s = 0.f;
    for (int i = tid; i < NTOK; i += 256) s += rn[b*NTOK + i];
    #pragma unroll
    for (int o = 1; o < 64; o <<= 1) s += __shfl_xor(s, o);
    __shared__ float red[4];
    if ((tid & 63) == 0) red[tid >> 6] = s;
    __syncthreads();
    if (tid == 0) it[b] = (red[0]+red[1]+red[2]+red[3]) / (float)NTOK * 0.125f;
}

// ---------------------------------------------------------------------------
__global__ __launch_bounds__(256) void l2n_s2s(const unsigned short* __restrict__ ih,
        const unsigned short* __restrict__ il,
        unsigned short* __restrict__ oh, unsigned short* __restrict__ ol)
{
    size_t row = (size_t)blockIdx.x*4 + (threadIdx.x >> 6);
    int lane = threadIdx.x & 63;
    size_t ii = row*HD + lane;
    float x = bf2f(ih[ii]) + bf2f(il[ii]);
    float s = x*x;
    #pragma unroll
    for (int o = 1; o < 64; o <<= 1) s += __shfl_xor(s, o);
    float xn = x / fmaxf(sqrtf(s), 1e-12f);
    unsigned short hv = f2bf(xn);
    oh[ii] = hv;
    ol[ii] = f2bf(xn - bf2f(hv));
}

// ---------------------------------------------------------------------------
extern "C" void kernel_launch(void* const* d_in, const int* in_sizes, int n_in,
                              void* d_out, int out_size, void* d_ws, size_t ws_size,
                              hipStream_t stream)
{
    const float* x      = (const float*)d_in[0];
    const float* qkv_w  = (const float*)d_in[1];
    const float* qkv_b  = (const float*)d_in[2];
    const float* proj_w = (const float*)d_in[3];
    const float* proj_b = (const float*)d_in[4];
    float* out = (float*)d_out;            // [0,SZ)=x_gem, [SZ,2SZ)=x_ori

    unsigned short* w16 = (unsigned short*)d_ws;
    #define SL(i) (w16 + (size_t)(i)*SZ)          // 8 bf16 slots
    unsigned short* WQh = w16 + 8*SZ;             // WQ, dead after qkv
    unsigned short* WQl = WQh + WSZ;
    unsigned short* VT1 = WQh;                    // aliases WQ
    size_t p = 8*SZ + 2*WSZ;
    unsigned short* VTv = w16 + p;  p += VTSZ;
    unsigned short* VT2 = w16 + p;  p += VTSZ;    // batched-only
    unsigned short* VT3 = w16 + p;  p += VTSZ;    // batched-only
    unsigned short* WPh = w16 + p;  p += PSZ;
    unsigned short* WPl = w16 + p;  p += PSZ;
    unsigned short* E0  = w16 + p;  p += SZ;      // batched-only extra pair
    unsigned short* E1  = w16 + p;  p += SZ;
    float* rn = (float*)(w16 + p);
    float* it = rn + M_ROWS;
    size_t need = (p + 2*(M_ROWS + 8)) * sizeof(unsigned short);
    int batched = (ws_size >= need);

    unsigned short* S0 = (unsigned short*)d_out;  // x_gem bytes (scratch pair)
    unsigned short* S1 = S0 + SZ;

    dim3 blk(256);
    dim3 gq(24,37), gp(8,73), gfl(640), gflb(640,3), gt(10,128);

    // common prologue
    row_norm<<<dim3(M_ROWS), blk, 0, stream>>>(x, rn);
    calc_invtemp<<<dim3(NB), blk, 0, stream>>>(rn, it);
    split_rows<<<dim3(M_ROWS), blk, 0, stream>>>(x, SL(6), SL(7), 1);
    split_rows<<<dim3(3*NC),  blk, 0, stream>>>(qkv_w, WQh, WQl, 0);
    gemm_qkv_mfma<<<gq, blk, 0, stream>>>(SL(6), SL(7), WQh, WQl, qkv_b,
        SL(0), SL(1), SL(2), SL(3), SL(4), SL(5));
    transp64<<<gt, blk, 0, stream>>>(SL(4), VTv);
    // x_ori = proj(softmax(q k^T/8) v)
    flash2<<<gfl, blk, 0, stream>>>(SL(0),SL(1),SL(2),SL(3), VTv,
        SL(6),SL(7), nullptr, 0.125f, 0);
    split_rows<<<dim3(NC), blk, 0, stream>>>(proj_w, WPh, WPl, 0);
    gemm_proj_mfma<<<gp, blk, 0, stream>>>(SL(6),SL(7), WPh,WPl, proj_b, 1.f,
        out + SZ);

    if (batched){
        // xs_i = l2n in-place on v(4,5), k(2,3), q(0,1); then transposes
        l2n_s2s<<<dim3(18464), blk, 0, stream>>>(SL(4),SL(5), SL(4),SL(5));
        l2n_s2s<<<dim3(18464), blk, 0, stream>>>(SL(2),SL(3), SL(2),SL(3));
        l2n_s2s<<<dim3(18464), blk, 0, stream>>>(SL(0),SL(1), SL(0),SL(1));
        transp64<<<gt, blk, 0, stream>>>(SL(4), VT1);
        transp64<<<gt, blk, 0, stream>>>(SL(2), VT2);
        transp64<<<gt, blk, 0, stream>>>(SL(0), VT3);
        // z_i = l2n(ys_i) fused in epilogue (VAR=1): outputs (6,7), S, E
        flash2b<1><<<gflb, blk, 0, stream>>>(
            SL(4),SL(5), SL(2),SL(3), SL(0),SL(1),
            VT1, VT2, VT3,
            SL(6),SL(7), S0,S1, E0,E1, it);
        // final attentions concurrently (VAR=2, V = original v via VTv)
        flash2b<2><<<gflb, blk, 0, stream>>>(
            SL(6),SL(7), S0,S1, E0,E1,
            VTv, VTv, VTv,
            SL(4),SL(5), SL(2),SL(3), SL(0),SL(1), it);
        sum3<<<dim3(4616), blk, 0, stream>>>(
            SL(4),SL(5), SL(2),SL(3), SL(0),SL(1), SL(4),SL(5));
        gemm_proj_mfma<<<gp, blk, 0, stream>>>(SL(4),SL(5), WPh,WPl, proj_b,
            1.f/3.f, out);
    } else {
        // proven serial fallback (R9-style, online softmax throughout)
        unsigned short* VTx = WQh;
        l2n_s2s<<<dim3(18464), blk, 0, stream>>>(SL(4),SL(5), SL(6),SL(7));
        transp64<<<gt, blk, 0, stream>>>(SL(6), VTx);
        flash2<<<gfl, blk, 0, stream>>>(SL(6),SL(7),SL(6),SL(7), VTx,
            SL(4),SL(5), it, 0.f, 0);
        l2n_s2s<<<dim3(18464), blk, 0, stream>>>(SL(4),SL(5), SL(6),SL(7));
        l2n_s2s<<<dim3(18464), blk, 0, stream>>>(SL(2),SL(3), SL(2),SL(3));
        transp64<<<gt, blk, 0, stream>>>(SL(2), VTx);
        flash2<<<gfl, blk, 0, stream>>>(SL(2),SL(3),SL(2),SL(3), VTx,
            SL(4),SL(5), it, 0.f, 0);
        l2n_s2s<<<dim3(18464), blk, 0, stream>>>(SL(4),SL(5), SL(2),SL(3));
        l2n_s2s<<<dim3(18464), blk, 0, stream>>>(SL(0),SL(1), SL(0),SL(1));
        transp64<<<gt, blk, 0, stream>>>(SL(0), VTx);
        flash2<<<gfl, blk, 0, stream>>>(SL(0),SL(1),SL(0),SL(1), VTx,
            SL(4),SL(5), it, 0.f, 0);
        l2n_s2s<<<dim3(18464), blk, 0, stream>>>(SL(4),SL(5), SL(0),SL(1));
        flash2<<<gfl, blk, 0, stream>>>(SL(6),SL(7),SL(6),SL(7), VTv,
            SL(4),SL(5), it, 0.f, 0);
        flash2<<<gfl, blk, 0, stream>>>(SL(2),SL(3),SL(2),SL(3), VTv,
            SL(4),SL(5), it, 0.f, 1);
        flash2<<<gfl, blk, 0, stream>>>(SL(0),SL(1),SL(0),SL(1), VTv,
            SL(4),SL(5), it, 0.f, 1);
        gemm_proj_mfma<<<gp, blk, 0, stream>>>(SL(4),SL(5), WPh,WPl, proj_b,
            1.f/3.f, out);
    }
    #undef SL
}